// Round 3
// 652.830 us; speedup vs baseline: 1.3094x; 1.3094x over previous
//
#include <hip/hip_runtime.h>

typedef unsigned short u16;
typedef unsigned int u32;
typedef __attribute__((ext_vector_type(8))) short s16x8;
typedef __attribute__((ext_vector_type(4))) float f32x4;

#define PIf 3.14159265358979323846f

__device__ __forceinline__ float bf2f(u16 u) {
    unsigned v = (unsigned)u << 16;
    return __builtin_bit_cast(float, v);
}
__device__ __forceinline__ u16 f2bf(float f) {
    unsigned u = __builtin_bit_cast(unsigned, f);
    u += 0x7fffu + ((u >> 16) & 1u);
    return (u16)(u >> 16);
}
__device__ __forceinline__ float b2f_lo(unsigned w) { return __builtin_bit_cast(float, w << 16); }
__device__ __forceinline__ float b2f_hi(unsigned w) { return __builtin_bit_cast(float, w & 0xffff0000u); }

// ws layout (bytes)
#define OFF_FLAG 0
#define OFF_WT   256
#define OFF_WCT  2097408
#define OFF_QB   2179328
#define OFF_KB   6373632
#define OFF_VB   10567936
#define OFF_XB   14762240
#define OFF_QP   31539456
#define OFF_KP   35733760
#define OFF_VP   39928064
#define OFF_VT   44122368
#define OFF_COEF 48316672
#define OFF_CTX  49627392
#define OFF_BIAS 53821696
#define OFF_INV  53829888
#define OFF_PBUF 53960960

// ---------------------------------------------------------------------------
// dtype probe: fp32 N(0,0.02) words all have |v| < 0.5; bf16-pair words
// reinterpret to ~2^100 magnitudes. flag = 1 -> inputs/outputs are fp32.
// ---------------------------------------------------------------------------
__global__ void kdetect(const u32* __restrict__ wq, int* __restrict__ flag) {
    int lane = threadIdx.x;
    float v = fabsf(__builtin_bit_cast(float, wq[lane]));
    bool smallv = (v > 1e-30f) && (v < 0.5f);
    unsigned long long m = __ballot(smallv);
    if (lane == 0) *flag = (__popcll(m) >= 32) ? 1 : 0;
}

// ---------------------------------------------------------------------------
// convert (or copy) an input tensor into a bf16 ws buffer
// ---------------------------------------------------------------------------
__global__ void kcvt(const void* __restrict__ src, u16* __restrict__ dst, int n,
                     const int* __restrict__ flag) {
    int i = (blockIdx.x * 256 + threadIdx.x) * 4;
    if (i >= n) return;
    if (*flag) {
        float4 f = *(const float4*)((const float*)src + i);
        u16 r[4] = {f2bf(f.x), f2bf(f.y), f2bf(f.z), f2bf(f.w)};
        *(uint2*)(dst + i) = *(const uint2*)r;
    } else {
        *(uint2*)(dst + i) = *(const uint2*)((const u16*)src + i);
    }
}

// biases: [bq 512][bk 512][bv 512][bo 512][bcoef 80] -> bf16 ws
__global__ void kbias(const void* __restrict__ bq, const void* __restrict__ bk,
                      const void* __restrict__ bv, const void* __restrict__ bo,
                      const void* __restrict__ bc, u16* __restrict__ dst,
                      const int* __restrict__ flag) {
    int t = threadIdx.x;  // 512
    bool f = *flag != 0;
    dst[t]        = f ? f2bf(((const float*)bq)[t]) : ((const u16*)bq)[t];
    dst[512 + t]  = f ? f2bf(((const float*)bk)[t]) : ((const u16*)bk)[t];
    dst[1024 + t] = f ? f2bf(((const float*)bv)[t]) : ((const u16*)bv)[t];
    dst[1536 + t] = f ? f2bf(((const float*)bo)[t]) : ((const u16*)bo)[t];
    if (t < 80)
        dst[2048 + t] = f ? f2bf(((const float*)bc)[t]) : ((const u16*)bc)[t];
}

// ---------------------------------------------------------------------------
// transpose the four 512x512 weight matrices (W[k][n] -> WT[n][k]), bf16 out
// ---------------------------------------------------------------------------
__global__ void ktrans512(const void* __restrict__ wq, const void* __restrict__ wk,
                          const void* __restrict__ wv, const void* __restrict__ wo,
                          u16* __restrict__ dst, const int* __restrict__ flag) {
    __shared__ u16 t[32][33];
    const void* srcs[4] = {wq, wk, wv, wo};
    const void* src = srcs[blockIdx.z];
    bool f = *flag != 0;
    u16* d = dst + (size_t)blockIdx.z * 512 * 512;
    int x0 = blockIdx.x * 32, y0 = blockIdx.y * 32;
    size_t si = (size_t)(y0 + threadIdx.y) * 512 + x0 + threadIdx.x;
    t[threadIdx.y][threadIdx.x] = f ? f2bf(((const float*)src)[si]) : ((const u16*)src)[si];
    __syncthreads();
    d[(size_t)(x0 + threadIdx.y) * 512 + y0 + threadIdx.x] = t[threadIdx.x][threadIdx.y];
}

// Wcoef (10,512,8) -> WcT[(n*8+h)][d], bf16
__global__ void kwct(const void* __restrict__ wc, u16* __restrict__ dst,
                     const int* __restrict__ flag) {
    int nh = blockIdx.x;  // 0..79
    int n = nh >> 3, h = nh & 7;
    bool f = *flag != 0;
    for (int d = threadIdx.x; d < 512; d += 64) {
        size_t si = ((size_t)n * 512 + d) * 8 + h;
        dst[nh * 512 + d] = f ? f2bf(((const float*)wc)[si]) : ((const u16*)wc)[si];
    }
}

// ---------------------------------------------------------------------------
// GEMM out[4096][512] = A[4096][512] @ BT^T + bias (all bf16, MFMA)
// ---------------------------------------------------------------------------
__global__ __launch_bounds__(256) void kgemm(const u16* __restrict__ A, const u16* __restrict__ BT,
                                             const u16* __restrict__ bias, u16* __restrict__ out) {
    __shared__ u16 As[64][40];
    __shared__ u16 Bs[64][40];
    int tid = threadIdx.x;
    int w = tid >> 6, lane = tid & 63, quad = lane >> 4, col = lane & 15;
    int m0 = blockIdx.y * 64, n0 = blockIdx.x * 64;
    int wm = (w >> 1) * 32, wn = (w & 1) * 32;
    int sr = tid >> 2, sc = tid & 3;
    f32x4 acc[2][2] = {};
    for (int kt = 0; kt < 512; kt += 32) {
        __syncthreads();
        *(uint4*)&As[sr][sc * 8] = *(const uint4*)&A[(size_t)(m0 + sr) * 512 + kt + sc * 8];
        *(uint4*)&Bs[sr][sc * 8] = *(const uint4*)&BT[(size_t)(n0 + sr) * 512 + kt + sc * 8];
        __syncthreads();
        s16x8 a[2], b[2];
        a[0] = *(const s16x8*)&As[wm + col][quad * 8];
        a[1] = *(const s16x8*)&As[wm + 16 + col][quad * 8];
        b[0] = *(const s16x8*)&Bs[wn + col][quad * 8];
        b[1] = *(const s16x8*)&Bs[wn + 16 + col][quad * 8];
#pragma unroll
        for (int mi = 0; mi < 2; mi++)
#pragma unroll
            for (int ni = 0; ni < 2; ni++)
                acc[mi][ni] = __builtin_amdgcn_mfma_f32_16x16x32_bf16(a[mi], b[ni], acc[mi][ni], 0, 0, 0);
    }
#pragma unroll
    for (int mi = 0; mi < 2; mi++)
#pragma unroll
        for (int ni = 0; ni < 2; ni++) {
            int n = n0 + wn + ni * 16 + col;
            float bv = bf2f(bias[n]);
#pragma unroll
            for (int r = 0; r < 4; r++) {
                int m = m0 + wm + mi * 16 + quad * 4 + r;
                out[(size_t)m * 512 + n] = f2bf(acc[mi][ni][r] + bv);
            }
        }
}

// final GEMM: same compute, dtype-selected store into d_out
template <int F32>
__global__ __launch_bounds__(256) void kgemm_final(const u16* __restrict__ A, const u16* __restrict__ BT,
                                                   const u16* __restrict__ bias, u16* __restrict__ outH,
                                                   float* __restrict__ outF, const int* __restrict__ flag) {
    if (*flag != F32) return;
    __shared__ u16 As[64][40];
    __shared__ u16 Bs[64][40];
    int tid = threadIdx.x;
    int w = tid >> 6, lane = tid & 63, quad = lane >> 4, col = lane & 15;
    int m0 = blockIdx.y * 64, n0 = blockIdx.x * 64;
    int wm = (w >> 1) * 32, wn = (w & 1) * 32;
    int sr = tid >> 2, sc = tid & 3;
    f32x4 acc[2][2] = {};
    for (int kt = 0; kt < 512; kt += 32) {
        __syncthreads();
        *(uint4*)&As[sr][sc * 8] = *(const uint4*)&A[(size_t)(m0 + sr) * 512 + kt + sc * 8];
        *(uint4*)&Bs[sr][sc * 8] = *(const uint4*)&BT[(size_t)(n0 + sr) * 512 + kt + sc * 8];
        __syncthreads();
        s16x8 a[2], b[2];
        a[0] = *(const s16x8*)&As[wm + col][quad * 8];
        a[1] = *(const s16x8*)&As[wm + 16 + col][quad * 8];
        b[0] = *(const s16x8*)&Bs[wn + col][quad * 8];
        b[1] = *(const s16x8*)&Bs[wn + 16 + col][quad * 8];
#pragma unroll
        for (int mi = 0; mi < 2; mi++)
#pragma unroll
            for (int ni = 0; ni < 2; ni++)
                acc[mi][ni] = __builtin_amdgcn_mfma_f32_16x16x32_bf16(a[mi], b[ni], acc[mi][ni], 0, 0, 0);
    }
#pragma unroll
    for (int mi = 0; mi < 2; mi++)
#pragma unroll
        for (int ni = 0; ni < 2; ni++) {
            int n = n0 + wn + ni * 16 + col;
            float bv = bf2f(bias[n]);
#pragma unroll
            for (int r = 0; r < 4; r++) {
                int m = m0 + wm + mi * 16 + quad * 4 + r;
                float val = acc[mi][ni][r] + bv;
                if constexpr (F32) outF[(size_t)m * 512 + n] = val;
                else               outH[(size_t)m * 512 + n] = f2bf(val);
            }
        }
}

// vp (B,S,D) -> vT[b][d][s]
__global__ void kvtrans(const u16* __restrict__ vp, u16* __restrict__ vT) {
    __shared__ u16 t[32][33];
    int b = blockIdx.z;
    int d0 = blockIdx.x * 32, s0 = blockIdx.y * 32;
    t[threadIdx.y][threadIdx.x] = vp[((size_t)b * 2048 + s0 + threadIdx.y) * 512 + d0 + threadIdx.x];
    __syncthreads();
    vT[((size_t)b * 512 + d0 + threadIdx.y) * 2048 + s0 + threadIdx.x] = t[threadIdx.x][threadIdx.y];
}

// ---------------------------------------------------------------------------
// coefs[(b*8+h)*10+n][s] (fp32, pre-scaled by 0.0125, abs on n==1)
// MFMA version: out[4096][80] = qp @ WcT^T, one 64-row tile per block.
// ---------------------------------------------------------------------------
__global__ __launch_bounds__(256) void kcoef(const u16* __restrict__ qp, const u16* __restrict__ wct,
                                             const u16* __restrict__ bc, float* __restrict__ cout) {
    __shared__ u16 As[64][40];
    int tid = threadIdx.x;
    int w = tid >> 6, lane = tid & 63, quad = lane >> 4, col = lane & 15;
    int m0 = blockIdx.x * 64;
    int sr = tid >> 2, sc = tid & 3;
    f32x4 acc[5] = {};
    for (int kt = 0; kt < 512; kt += 32) {
        __syncthreads();
        *(uint4*)&As[sr][sc * 8] = *(const uint4*)&qp[(size_t)(m0 + sr) * 512 + kt + sc * 8];
        __syncthreads();
        s16x8 a = *(const s16x8*)&As[w * 16 + col][quad * 8];
#pragma unroll
        for (int nt = 0; nt < 5; nt++) {
            uint4 bv4 = *(const uint4*)&wct[(size_t)(nt * 16 + col) * 512 + kt + quad * 8];
            acc[nt] = __builtin_amdgcn_mfma_f32_16x16x32_bf16(a, __builtin_bit_cast(s16x8, bv4), acc[nt], 0, 0, 0);
        }
    }
    int m = m0 + w * 16 + quad * 4;  // +r below; all 4 rows share b (tiles don't straddle 2048)
    int b = m >> 11, s = m & 2047;
#pragma unroll
    for (int nt = 0; nt < 5; nt++) {
        int nh = nt * 16 + col, n = nh >> 3, h = nh & 7;
        float bvv = bf2f(bc[nh]);
        float4 o;
        float tmp[4];
#pragma unroll
        for (int r = 0; r < 4; r++) {
            float c = acc[nt][r] + bvv;
            if (n == 1) c = fabsf(c);
            tmp[r] = c * 0.0125f;  // 0.1 * (1/sqrt(64))
        }
        o.x = tmp[0]; o.y = tmp[1]; o.z = tmp[2]; o.w = tmp[3];
        *(float4*)&cout[((size_t)((b * 8 + h) * 10 + n)) * 2048 + s] = o;
    }
}

// ---------------------------------------------------------------------------
// fused attention sweep: QK^T MFMA + basis + exp -> p~ stored ONCE
// (bf16 to pbuf/attnH, or fp32 to attnF in the small-ws fallback), p~ also
// written in place into the xs LDS tile = free transpose for the immediate
// PV MFMA. Row sums reduced in-register; ctx scaled by 1/sum at epilogue.
// MODE 0: flag==0, p~ bf16 -> attnH (d_out).    normalize in place later.
// MODE 1: flag==1, p~ bf16 -> pbuf (ws).        expand to attnF later.
// MODE 2: flag==1, p~ fp32 -> attnF (fallback). normalize in place later.
// ---------------------------------------------------------------------------
template <int MODE>
__global__ __launch_bounds__(256) void kattn_f(const u16* __restrict__ qp, const u16* __restrict__ kp,
                                               const u16* __restrict__ vT, const u16* __restrict__ xd,
                                               const float* __restrict__ coef,
                                               u16* __restrict__ p16, float* __restrict__ p32,
                                               u16* __restrict__ ctx, float* __restrict__ invb,
                                               const int* __restrict__ flag) {
    if constexpr (MODE == 0) { if (*flag != 0) return; }
    else                     { if (*flag != 1) return; }
    __shared__ u16 qs[64][72];
    __shared__ u16 ks[128][72];
    __shared__ u16 xs[64][136];
    __shared__ float cfl[10][64];

    int tid = threadIdx.x;
    int w = tid >> 6, lane = tid & 63, quad = lane >> 4, col = lane & 15;
    int qt = blockIdx.x, bh = blockIdx.y;
    int b = bh >> 3, h = bh & 7;
    int q0 = qt * 64;

    {
        int r = tid >> 2, qu = tid & 3;
        const u16* src = qp + ((size_t)(b * 2048 + q0 + r)) * 512 + h * 64 + qu * 16;
        *(uint4*)&qs[r][qu * 16] = *(const uint4*)&src[0];
        *(uint4*)&qs[r][qu * 16 + 8] = *(const uint4*)&src[8];
    }
    if (tid < 160) {
        int n = tid >> 4, i = tid & 15;
        *(float4*)&cfl[n][i * 4] = *(const float4*)&coef[((size_t)(bh * 10 + n)) * 2048 + q0 + i * 4];
    }
    __syncthreads();

    float cf[40];
#pragma unroll
    for (int n = 0; n < 10; n++)
#pragma unroll
        for (int r = 0; r < 4; r++) cf[n * 4 + r] = cfl[n][w * 16 + quad * 4 + r];

    s16x8 a0 = *(const s16x8*)&qs[w * 16 + col][quad * 8];
    s16x8 a1 = *(const s16x8*)&qs[w * 16 + col][32 + quad * 8];

    float s_l[4] = {0.f, 0.f, 0.f, 0.f};
    f32x4 accv[4] = {};

    size_t abase = ((size_t)(bh * 2048 + q0)) * 2048;
    const u16* vb0 = vT + ((size_t)(b * 512 + h * 64 + col)) * 2048 + quad * 8;

    for (int k0 = 0; k0 < 2048; k0 += 128) {
        __syncthreads();
        {
            int kr = tid >> 1, hf = tid & 1;
            const u16* src = kp + ((size_t)(b * 2048 + k0 + kr)) * 512 + h * 64 + hf * 32;
#pragma unroll
            for (int i = 0; i < 4; i++) *(uint4*)&ks[kr][hf * 32 + i * 8] = *(const uint4*)&src[i * 8];
        }
        {
            int qr = tid >> 2, qu = tid & 3;
            const u16* src = xd + ((size_t)(b * 2048 + q0 + qr)) * 2048 + k0 + qu * 32;
#pragma unroll
            for (int i = 0; i < 4; i++) *(uint4*)&xs[qr][qu * 32 + i * 8] = *(const uint4*)&src[i * 8];
        }
        __syncthreads();
#pragma unroll
        for (int nt = 0; nt < 8; nt++) {
            s16x8 b0 = *(const s16x8*)&ks[nt * 16 + col][quad * 8];
            s16x8 b1 = *(const s16x8*)&ks[nt * 16 + col][32 + quad * 8];
            f32x4 acc = {0.f, 0.f, 0.f, 0.f};
            acc = __builtin_amdgcn_mfma_f32_16x16x32_bf16(a0, b0, acc, 0, 0, 0);
            acc = __builtin_amdgcn_mfma_f32_16x16x32_bf16(a1, b1, acc, 0, 0, 0);
#pragma unroll
            for (int r = 0; r < 4; r++) {
                int lq = w * 16 + quad * 4 + r;
                int kk = nt * 16 + col;
                float x = bf2f(xs[lq][kk]);
                float ang = PIf * x;
                float s1 = __sinf(ang), c1 = __cosf(ang);
                float s2 = 2.f * s1 * c1, c2 = 1.f - 2.f * s1 * s1;
                float s3 = s1 * c2 + c1 * s2, c3 = c1 * c2 - s1 * s2;
                float s5 = s3 * c2 + c3 * s2, c5 = c3 * c2 - s3 * s2;
                float s4 = 2.f * s2 * c2, c4 = 1.f - 2.f * s2 * s2;
                float s9 = s5 * c4 + c5 * s4, c9 = c5 * c4 - s5 * s4;
                float dot = cf[0 * 4 + r] * x + cf[1 * 4 + r] * (-0.5f * x * x)
                          + cf[2 * 4 + r] * s1 + cf[3 * 4 + r] * c1
                          + cf[4 * 4 + r] * s3 + cf[5 * 4 + r] * c3
                          + cf[6 * 4 + r] * s5 + cf[7 * 4 + r] * c5
                          + cf[8 * 4 + r] * s9 + cf[9 * 4 + r] * c9;
                float logit = acc[r] * 0.125f + dot;
                float p = __expf(logit);
                size_t idx = abase + (size_t)lq * 2048 + k0 + kk;
                u16 pb = f2bf(p);
                if constexpr (MODE == 2) p32[idx] = p;
                else                     p16[idx] = pb;
                s_l[r] += p;
                xs[lq][kk] = pb;  // in-place LDS transpose source for PV
            }
        }
        // PV on this 128-k chunk: wave-private rows of xs now hold bf16 p~
#pragma unroll
        for (int kc = 0; kc < 4; kc++) {
            s16x8 af = *(const s16x8*)&xs[w * 16 + col][kc * 32 + quad * 8];
#pragma unroll
            for (int nt = 0; nt < 4; nt++) {
                uint4 bv4 = *(const uint4*)&vb0[(size_t)nt * 16 * 2048 + k0 + kc * 32];
                accv[nt] = __builtin_amdgcn_mfma_f32_16x16x32_bf16(af, __builtin_bit_cast(s16x8, bv4), accv[nt], 0, 0, 0);
            }
        }
    }

    // per-row sums across the 16 lanes of each quad -> inv, kept in-register
    float inv_r[4];
#pragma unroll
    for (int r = 0; r < 4; r++) {
        float s = s_l[r];
#pragma unroll
        for (int off = 1; off < 16; off <<= 1) s += __shfl_xor(s, off);
        inv_r[r] = 1.f / s;
    }
    if (col == 0) {
#pragma unroll
        for (int r = 0; r < 4; r++)
            invb[bh * 2048 + q0 + w * 16 + quad * 4 + r] = inv_r[r];
    }
#pragma unroll
    for (int nt = 0; nt < 4; nt++)
#pragma unroll
        for (int r = 0; r < 4; r++) {
            int q = q0 + w * 16 + quad * 4 + r;
            int d = h * 64 + nt * 16 + col;
            ctx[((size_t)(b * 2048 + q)) * 512 + d] = f2bf(accv[nt][r] * inv_r[r]);
        }
}

// ---------------------------------------------------------------------------
// normalize p~ -> attn output. One block per attention row (full occupancy).
// MODE 0: in-place bf16 scale on attnH.
// MODE 1: bf16 pbuf -> fp32 attnF.
// MODE 2: in-place fp32 scale on attnF.
// ---------------------------------------------------------------------------
template <int MODE>
__global__ __launch_bounds__(256) void knorm(u16* __restrict__ p16, float* __restrict__ p32,
                                             const float* __restrict__ invb, const int* __restrict__ flag) {
    if constexpr (MODE == 0) { if (*flag != 0) return; }
    else                     { if (*flag != 1) return; }
    int row = blockIdx.x;  // 0..32767 = bh*2048 + q
    float inv = invb[row];
    size_t base = (size_t)row * 2048 + threadIdx.x * 8;
    if constexpr (MODE == 0) {
        uint4 vv = *(const uint4*)&p16[base];
        unsigned a[4] = {vv.x, vv.y, vv.z, vv.w};
#pragma unroll
        for (int i = 0; i < 4; i++) {
            float lo = b2f_lo(a[i]) * inv;
            float hi = b2f_hi(a[i]) * inv;
            a[i] = ((unsigned)f2bf(hi) << 16) | (unsigned)f2bf(lo);
        }
        uint4 o; o.x = a[0]; o.y = a[1]; o.z = a[2]; o.w = a[3];
        *(uint4*)&p16[base] = o;
    } else if constexpr (MODE == 1) {
        uint4 vv = *(const uint4*)&p16[base];
        unsigned a[4] = {vv.x, vv.y, vv.z, vv.w};
        float4 o0, o1;
        o0.x = b2f_lo(a[0]) * inv; o0.y = b2f_hi(a[0]) * inv;
        o0.z = b2f_lo(a[1]) * inv; o0.w = b2f_hi(a[1]) * inv;
        o1.x = b2f_lo(a[2]) * inv; o1.y = b2f_hi(a[2]) * inv;
        o1.z = b2f_lo(a[3]) * inv; o1.w = b2f_hi(a[3]) * inv;
        *(float4*)&p32[base] = o0;
        *(float4*)&p32[base + 4] = o1;
    } else {
        float4 v0 = *(const float4*)&p32[base];
        float4 v1 = *(const float4*)&p32[base + 4];
        v0.x *= inv; v0.y *= inv; v0.z *= inv; v0.w *= inv;
        v1.x *= inv; v1.y *= inv; v1.z *= inv; v1.w *= inv;
        *(float4*)&p32[base] = v0;
        *(float4*)&p32[base + 4] = v1;
    }
}

// ---------------------------------------------------------------------------
// launch
// ---------------------------------------------------------------------------
extern "C" void kernel_launch(void* const* d_in, const int* in_sizes, int n_in,
                              void* d_out, int out_size, void* d_ws, size_t ws_size,
                              hipStream_t stream) {
    const void* q  = d_in[0];
    const void* k  = d_in[1];
    const void* v  = d_in[2];
    const void* xd = d_in[3];
    const void* Wq = d_in[4];
    const void* bq = d_in[5];
    const void* Wk = d_in[6];
    const void* bk = d_in[7];
    const void* Wv = d_in[8];
    const void* bv = d_in[9];
    const void* Wc = d_in[10];
    const void* bc = d_in[11];
    const void* Wo = d_in[12];
    const void* bo = d_in[13];

    char* ws = (char*)d_ws;
    int*   flag = (int*)(ws + OFF_FLAG);
    u16*   WT   = (u16*)(ws + OFF_WT);
    u16*   WcT  = (u16*)(ws + OFF_WCT);
    u16*   qb   = (u16*)(ws + OFF_QB);
    u16*   kb   = (u16*)(ws + OFF_KB);
    u16*   vb   = (u16*)(ws + OFF_VB);
    u16*   xb   = (u16*)(ws + OFF_XB);
    u16*   qp   = (u16*)(ws + OFF_QP);
    u16*   kp   = (u16*)(ws + OFF_KP);
    u16*   vp   = (u16*)(ws + OFF_VP);
    u16*   vT   = (u16*)(ws + OFF_VT);
    float* coef = (float*)(ws + OFF_COEF);
    u16*   ctx  = (u16*)(ws + OFF_CTX);
    u16*   bB   = (u16*)(ws + OFF_BIAS);
    float* invb = (float*)(ws + OFF_INV);
    u16*   pbuf = (u16*)(ws + OFF_PBUF);

    u16*   outH  = (u16*)d_out;
    u16*   attnH = outH + 2097152;
    float* outF  = (float*)d_out;
    float* attnF = outF + 2097152;

    // bf16 p~ staging buffer needs 134 MB of ws; fall back to fp32-in-place if absent
    bool big = ws_size >= (size_t)OFF_PBUF + 134217728ull;

    kdetect<<<1, 64, 0, stream>>>((const u32*)Wq, flag);
    kcvt<<<2048, 256, 0, stream>>>(q, qb, 2097152, flag);
    kcvt<<<2048, 256, 0, stream>>>(k, kb, 2097152, flag);
    kcvt<<<2048, 256, 0, stream>>>(v, vb, 2097152, flag);
    kcvt<<<8192, 256, 0, stream>>>(xd, xb, 8388608, flag);
    kbias<<<1, 512, 0, stream>>>(bq, bk, bv, bo, bc, bB, flag);
    ktrans512<<<dim3(16, 16, 4), dim3(32, 32), 0, stream>>>(Wq, Wk, Wv, Wo, WT, flag);
    kwct<<<80, 64, 0, stream>>>(Wc, WcT, flag);
    kgemm<<<dim3(8, 64), 256, 0, stream>>>(qb, WT, bB, qp);
    kgemm<<<dim3(8, 64), 256, 0, stream>>>(kb, WT + 262144, bB + 512, kp);
    kgemm<<<dim3(8, 64), 256, 0, stream>>>(vb, WT + 524288, bB + 1024, vp);
    kvtrans<<<dim3(16, 64, 2), dim3(32, 32), 0, stream>>>(vp, vT);
    kcoef<<<64, 256, 0, stream>>>(qp, WcT, bB + 2048, coef);

    kattn_f<0><<<dim3(32, 16), 256, 0, stream>>>(qp, kp, vT, xb, coef, attnH, attnF, ctx, invb, flag);
    if (big)
        kattn_f<1><<<dim3(32, 16), 256, 0, stream>>>(qp, kp, vT, xb, coef, pbuf, attnF, ctx, invb, flag);
    else
        kattn_f<2><<<dim3(32, 16), 256, 0, stream>>>(qp, kp, vT, xb, coef, attnH, attnF, ctx, invb, flag);

    knorm<0><<<32768, 256, 0, stream>>>(attnH, attnF, invb, flag);
    if (big)
        knorm<1><<<32768, 256, 0, stream>>>(pbuf, attnF, invb, flag);
    else
        knorm<2><<<32768, 256, 0, stream>>>(attnH, attnF, invb, flag);

    kgemm_final<0><<<dim3(8, 64), 256, 0, stream>>>(ctx, WT + 786432, bB + 1536, outH, outF, flag);
    kgemm_final<1><<<dim3(8, 64), 256, 0, stream>>>(ctx, WT + 786432, bB + 1536, outH, outF, flag);
}

// Round 6
// 637.901 us; speedup vs baseline: 1.3400x; 1.0234x over previous
//
#include <hip/hip_runtime.h>

typedef unsigned short u16;
typedef unsigned int u32;
typedef __attribute__((ext_vector_type(8))) short s16x8;
typedef __attribute__((ext_vector_type(4))) float f32x4;

#define PIf 3.14159265358979323846f

__device__ __forceinline__ float bf2f(u16 u) {
    unsigned v = (unsigned)u << 16;
    return __builtin_bit_cast(float, v);
}
__device__ __forceinline__ u16 f2bf(float f) {
    unsigned u = __builtin_bit_cast(unsigned, f);
    u += 0x7fffu + ((u >> 16) & 1u);
    return (u16)(u >> 16);
}
__device__ __forceinline__ float b2f_lo(unsigned w) { return __builtin_bit_cast(float, w << 16); }
__device__ __forceinline__ float b2f_hi(unsigned w) { return __builtin_bit_cast(float, w & 0xffff0000u); }

// ws layout (bytes)
#define OFF_FLAG 0
#define OFF_WT   256
#define OFF_WCT  2097408
#define OFF_QB   2179328
#define OFF_KB   6373632
#define OFF_VB   10567936
#define OFF_XB   14762240
#define OFF_QP   31539456
#define OFF_KP   35733760
#define OFF_VP   39928064
#define OFF_VT   44122368
#define OFF_COEF 48316672
#define OFF_CTX  49627392
#define OFF_BIAS 53821696
#define OFF_INV  53829888
#define OFF_PBUF 53960960

// ---------------------------------------------------------------------------
// dtype probe: fp32 N(0,0.02) words all have |v| < 0.5; bf16-pair words
// reinterpret to ~2^100 magnitudes. flag = 1 -> inputs/outputs are fp32.
// ---------------------------------------------------------------------------
__global__ void kdetect(const u32* __restrict__ wq, int* __restrict__ flag) {
    int lane = threadIdx.x;
    float v = fabsf(__builtin_bit_cast(float, wq[lane]));
    bool smallv = (v > 1e-30f) && (v < 0.5f);
    unsigned long long m = __ballot(smallv);
    if (lane == 0) *flag = (__popcll(m) >= 32) ? 1 : 0;
}

// ---------------------------------------------------------------------------
// convert (or copy) q,k,v (blockIdx.y selects) into contiguous bf16 ws buffers
// ---------------------------------------------------------------------------
__global__ void kcvt3(const void* __restrict__ s0, const void* __restrict__ s1,
                      const void* __restrict__ s2, u16* __restrict__ dst,
                      const int* __restrict__ flag) {
    const void* srcs[3] = {s0, s1, s2};
    const void* src = srcs[blockIdx.y];
    u16* d = dst + (size_t)blockIdx.y * 2097152;
    int i = (blockIdx.x * 256 + threadIdx.x) * 4;
    if (*flag) {
        float4 f = *(const float4*)((const float*)src + i);
        u16 r[4] = {f2bf(f.x), f2bf(f.y), f2bf(f.z), f2bf(f.w)};
        *(uint2*)(d + i) = *(const uint2*)r;
    } else {
        *(uint2*)(d + i) = *(const uint2*)((const u16*)src + i);
    }
}

__global__ void kcvt(const void* __restrict__ src, u16* __restrict__ dst, int n,
                     const int* __restrict__ flag) {
    int i = (blockIdx.x * 256 + threadIdx.x) * 4;
    if (i >= n) return;
    if (*flag) {
        float4 f = *(const float4*)((const float*)src + i);
        u16 r[4] = {f2bf(f.x), f2bf(f.y), f2bf(f.z), f2bf(f.w)};
        *(uint2*)(dst + i) = *(const uint2*)r;
    } else {
        *(uint2*)(dst + i) = *(const uint2*)((const u16*)src + i);
    }
}

// biases: [bq 512][bk 512][bv 512][bo 512][bcoef 80] -> bf16 ws
__global__ void kbias(const void* __restrict__ bq, const void* __restrict__ bk,
                      const void* __restrict__ bv, const void* __restrict__ bo,
                      const void* __restrict__ bc, u16* __restrict__ dst,
                      const int* __restrict__ flag) {
    int t = threadIdx.x;  // 512
    bool f = *flag != 0;
    dst[t]        = f ? f2bf(((const float*)bq)[t]) : ((const u16*)bq)[t];
    dst[512 + t]  = f ? f2bf(((const float*)bk)[t]) : ((const u16*)bk)[t];
    dst[1024 + t] = f ? f2bf(((const float*)bv)[t]) : ((const u16*)bv)[t];
    dst[1536 + t] = f ? f2bf(((const float*)bo)[t]) : ((const u16*)bo)[t];
    if (t < 80)
        dst[2048 + t] = f ? f2bf(((const float*)bc)[t]) : ((const u16*)bc)[t];
}

// ---------------------------------------------------------------------------
// transpose the four 512x512 weight matrices (W[k][n] -> WT[n][k]), bf16 out
// ---------------------------------------------------------------------------
__global__ void ktrans512(const void* __restrict__ wq, const void* __restrict__ wk,
                          const void* __restrict__ wv, const void* __restrict__ wo,
                          u16* __restrict__ dst, const int* __restrict__ flag) {
    __shared__ u16 t[32][33];
    const void* srcs[4] = {wq, wk, wv, wo};
    const void* src = srcs[blockIdx.z];
    bool f = *flag != 0;
    u16* d = dst + (size_t)blockIdx.z * 512 * 512;
    int x0 = blockIdx.x * 32, y0 = blockIdx.y * 32;
    size_t si = (size_t)(y0 + threadIdx.y) * 512 + x0 + threadIdx.x;
    t[threadIdx.y][threadIdx.x] = f ? f2bf(((const float*)src)[si]) : ((const u16*)src)[si];
    __syncthreads();
    d[(size_t)(x0 + threadIdx.y) * 512 + y0 + threadIdx.x] = t[threadIdx.x][threadIdx.y];
}

// Wcoef (10,512,8) -> WcT[(n*8+h)][d], bf16
__global__ void kwct(const void* __restrict__ wc, u16* __restrict__ dst,
                     const int* __restrict__ flag) {
    int nh = blockIdx.x;  // 0..79
    int n = nh >> 3, h = nh & 7;
    bool f = *flag != 0;
    for (int d = threadIdx.x; d < 512; d += 64) {
        size_t si = ((size_t)n * 512 + d) * 8 + h;
        dst[nh * 512 + d] = f ? f2bf(((const float*)wc)[si]) : ((const u16*)wc)[si];
    }
}

// ---------------------------------------------------------------------------
// GEMM out[4096][512] = A[4096][512] @ BT^T + bias (all bf16, MFMA)
// ---------------------------------------------------------------------------
__global__ __launch_bounds__(256) void kgemm(const u16* __restrict__ A, const u16* __restrict__ BT,
                                             const u16* __restrict__ bias, u16* __restrict__ out) {
    __shared__ u16 As[64][40];
    __shared__ u16 Bs[64][40];
    int tid = threadIdx.x;
    int w = tid >> 6, lane = tid & 63, quad = lane >> 4, col = lane & 15;
    int m0 = blockIdx.y * 64, n0 = blockIdx.x * 64;
    int wm = (w >> 1) * 32, wn = (w & 1) * 32;
    int sr = tid >> 2, sc = tid & 3;
    f32x4 acc[2][2] = {};
    for (int kt = 0; kt < 512; kt += 32) {
        __syncthreads();
        *(uint4*)&As[sr][sc * 8] = *(const uint4*)&A[(size_t)(m0 + sr) * 512 + kt + sc * 8];
        *(uint4*)&Bs[sr][sc * 8] = *(const uint4*)&BT[(size_t)(n0 + sr) * 512 + kt + sc * 8];
        __syncthreads();
        s16x8 a[2], b[2];
        a[0] = *(const s16x8*)&As[wm + col][quad * 8];
        a[1] = *(const s16x8*)&As[wm + 16 + col][quad * 8];
        b[0] = *(const s16x8*)&Bs[wn + col][quad * 8];
        b[1] = *(const s16x8*)&Bs[wn + 16 + col][quad * 8];
#pragma unroll
        for (int mi = 0; mi < 2; mi++)
#pragma unroll
            for (int ni = 0; ni < 2; ni++)
                acc[mi][ni] = __builtin_amdgcn_mfma_f32_16x16x32_bf16(a[mi], b[ni], acc[mi][ni], 0, 0, 0);
    }
#pragma unroll
    for (int mi = 0; mi < 2; mi++)
#pragma unroll
        for (int ni = 0; ni < 2; ni++) {
            int n = n0 + wn + ni * 16 + col;
            float bv = bf2f(bias[n]);
#pragma unroll
            for (int r = 0; r < 4; r++) {
                int m = m0 + wm + mi * 16 + quad * 4 + r;
                out[(size_t)m * 512 + n] = f2bf(acc[mi][ni][r] + bv);
            }
        }
}

// final GEMM: same compute, runtime dtype-selected store into d_out (1 launch)
__global__ __launch_bounds__(256) void kgemm_final(const u16* __restrict__ A, const u16* __restrict__ BT,
                                                   const u16* __restrict__ bias, u16* __restrict__ outH,
                                                   float* __restrict__ outF, const int* __restrict__ flag) {
    bool f32o = *flag != 0;
    __shared__ u16 As[64][40];
    __shared__ u16 Bs[64][40];
    int tid = threadIdx.x;
    int w = tid >> 6, lane = tid & 63, quad = lane >> 4, col = lane & 15;
    int m0 = blockIdx.y * 64, n0 = blockIdx.x * 64;
    int wm = (w >> 1) * 32, wn = (w & 1) * 32;
    int sr = tid >> 2, sc = tid & 3;
    f32x4 acc[2][2] = {};
    for (int kt = 0; kt < 512; kt += 32) {
        __syncthreads();
        *(uint4*)&As[sr][sc * 8] = *(const uint4*)&A[(size_t)(m0 + sr) * 512 + kt + sc * 8];
        *(uint4*)&Bs[sr][sc * 8] = *(const uint4*)&BT[(size_t)(n0 + sr) * 512 + kt + sc * 8];
        __syncthreads();
        s16x8 a[2], b[2];
        a[0] = *(const s16x8*)&As[wm + col][quad * 8];
        a[1] = *(const s16x8*)&As[wm + 16 + col][quad * 8];
        b[0] = *(const s16x8*)&Bs[wn + col][quad * 8];
        b[1] = *(const s16x8*)&Bs[wn + 16 + col][quad * 8];
#pragma unroll
        for (int mi = 0; mi < 2; mi++)
#pragma unroll
            for (int ni = 0; ni < 2; ni++)
                acc[mi][ni] = __builtin_amdgcn_mfma_f32_16x16x32_bf16(a[mi], b[ni], acc[mi][ni], 0, 0, 0);
    }
#pragma unroll
    for (int mi = 0; mi < 2; mi++)
#pragma unroll
        for (int ni = 0; ni < 2; ni++) {
            int n = n0 + wn + ni * 16 + col;
            float bv = bf2f(bias[n]);
#pragma unroll
            for (int r = 0; r < 4; r++) {
                int m = m0 + wm + mi * 16 + quad * 4 + r;
                float val = acc[mi][ni][r] + bv;
                if (f32o) outF[(size_t)m * 512 + n] = val;
                else      outH[(size_t)m * 512 + n] = f2bf(val);
            }
        }
}

// vp (B,S,D) -> vT[b][d][s]
__global__ void kvtrans(const u16* __restrict__ vp, u16* __restrict__ vT) {
    __shared__ u16 t[32][33];
    int b = blockIdx.z;
    int d0 = blockIdx.x * 32, s0 = blockIdx.y * 32;
    t[threadIdx.y][threadIdx.x] = vp[((size_t)b * 2048 + s0 + threadIdx.y) * 512 + d0 + threadIdx.x];
    __syncthreads();
    vT[((size_t)b * 512 + d0 + threadIdx.y) * 2048 + s0 + threadIdx.x] = t[threadIdx.x][threadIdx.y];
}

// ---------------------------------------------------------------------------
// coefs[(b*8+h)*10+n][s] (fp32, pre-scaled by 0.0125, abs on n==1)
// MFMA version: out[4096][80] = qp @ WcT^T, one 64-row tile per block.
// ---------------------------------------------------------------------------
__global__ __launch_bounds__(256) void kcoef(const u16* __restrict__ qp, const u16* __restrict__ wct,
                                             const u16* __restrict__ bc, float* __restrict__ cout) {
    __shared__ u16 As[64][40];
    int tid = threadIdx.x;
    int w = tid >> 6, lane = tid & 63, quad = lane >> 4, col = lane & 15;
    int m0 = blockIdx.x * 64;
    int sr = tid >> 2, sc = tid & 3;
    f32x4 acc[5] = {};
    for (int kt = 0; kt < 512; kt += 32) {
        __syncthreads();
        *(uint4*)&As[sr][sc * 8] = *(const uint4*)&qp[(size_t)(m0 + sr) * 512 + kt + sc * 8];
        __syncthreads();
        s16x8 a = *(const s16x8*)&As[w * 16 + col][quad * 8];
#pragma unroll
        for (int nt = 0; nt < 5; nt++) {
            uint4 bv4 = *(const uint4*)&wct[(size_t)(nt * 16 + col) * 512 + kt + quad * 8];
            acc[nt] = __builtin_amdgcn_mfma_f32_16x16x32_bf16(a, __builtin_bit_cast(s16x8, bv4), acc[nt], 0, 0, 0);
        }
    }
    int m = m0 + w * 16 + quad * 4;
    int b = m >> 11, s = m & 2047;
#pragma unroll
    for (int nt = 0; nt < 5; nt++) {
        int nh = nt * 16 + col, n = nh >> 3, h = nh & 7;
        float bvv = bf2f(bc[nh]);
        float4 o;
        float tmp[4];
#pragma unroll
        for (int r = 0; r < 4; r++) {
            float c = acc[nt][r] + bvv;
            if (n == 1) c = fabsf(c);
            tmp[r] = c * 0.0125f;  // 0.1 * (1/sqrt(64))
        }
        o.x = tmp[0]; o.y = tmp[1]; o.z = tmp[2]; o.w = tmp[3];
        *(float4*)&cout[((size_t)((b * 8 + h) * 10 + n)) * 2048 + s] = o;
    }
}

// ---------------------------------------------------------------------------
// fused attention sweep, 8 waves (512 thr): wave (wr,wc) = row-tile wr,
// k-half wc. QK^T MFMA + basis + exp -> p~ stored ONCE; p~ also written in
// place into the wave-private xs sub-block = free transpose for immediate PV.
// Cross-wave combine of partial PV accumulators + row sums via reclaimed LDS.
// F32S=0: bf16 p~ -> attnH (flag 0) or pbuf (flag 1 & big ws).
// F32S=1: fp32 p~ -> attnF (flag 1, small-ws fallback).
// ---------------------------------------------------------------------------
template <int F32S>
__global__ __launch_bounds__(512) void kattn_t(const u16* __restrict__ qp, const u16* __restrict__ kp,
                                               const u16* __restrict__ vT, const u16* __restrict__ xd,
                                               const float* __restrict__ coef,
                                               u16* __restrict__ attnH, u16* __restrict__ pbuf,
                                               float* __restrict__ p32,
                                               u16* __restrict__ ctx, float* __restrict__ invb,
                                               const int* __restrict__ flag, int big) {
    int fl = *flag;
    if constexpr (F32S) { if (fl != 1) return; }        // only small-ws fp32 path
    else                { if (fl && !big) return; }      // fp32 handled by F32S=1
    u16* p16 = fl ? pbuf : attnH;

    __shared__ u16 qs[64][72];
    __shared__ u16 ks[128][72];
    __shared__ u16 xs[64][136];
    __shared__ float cfl[10][64];

    int tid = threadIdx.x;
    int lane = tid & 63, quad = lane >> 4, col = lane & 15;
    int w = tid >> 6;
    int wr = w & 3, wc = w >> 2;
    int qt = blockIdx.x, bh = blockIdx.y;
    int b = bh >> 3, h = bh & 7;
    int q0 = qt * 64;

    {
        int r = tid >> 3, qu = tid & 7;
        const u16* src = qp + ((size_t)(b * 2048 + q0 + r)) * 512 + h * 64 + qu * 8;
        *(uint4*)&qs[r][qu * 8] = *(const uint4*)src;
    }
    if (tid < 160) {
        int n = tid >> 4, i = tid & 15;
        *(float4*)&cfl[n][i * 4] = *(const float4*)&coef[((size_t)(bh * 10 + n)) * 2048 + q0 + i * 4];
    }
    __syncthreads();

    float cf[40];
#pragma unroll
    for (int n = 0; n < 10; n++)
#pragma unroll
        for (int r = 0; r < 4; r++) cf[n * 4 + r] = cfl[n][wr * 16 + quad * 4 + r];

    s16x8 a0 = *(const s16x8*)&qs[wr * 16 + col][quad * 8];
    s16x8 a1 = *(const s16x8*)&qs[wr * 16 + col][32 + quad * 8];

    float s_l[4] = {0.f, 0.f, 0.f, 0.f};
    f32x4 accv[4] = {};

    size_t abase = ((size_t)(bh * 2048 + q0)) * 2048;
    const u16* vb0 = vT + ((size_t)(b * 512 + h * 64 + col)) * 2048 + quad * 8;

    for (int k0 = 0; k0 < 2048; k0 += 128) {
        __syncthreads();
        {
            int kr = tid >> 2, hf = tid & 3;
            const u16* src = kp + ((size_t)(b * 2048 + k0 + kr)) * 512 + h * 64 + hf * 16;
            *(uint4*)&ks[kr][hf * 16]     = *(const uint4*)&src[0];
            *(uint4*)&ks[kr][hf * 16 + 8] = *(const uint4*)&src[8];
        }
        {
            int qr = tid >> 3, qu = tid & 7;
            const u16* src = xd + ((size_t)(b * 2048 + q0 + qr)) * 2048 + k0 + qu * 16;
            *(uint4*)&xs[qr][qu * 16]     = *(const uint4*)&src[0];
            *(uint4*)&xs[qr][qu * 16 + 8] = *(const uint4*)&src[8];
        }
        __syncthreads();
#pragma unroll
        for (int nt = 0; nt < 4; nt++) {
            int ntg = wc * 4 + nt;
            s16x8 b0 = *(const s16x8*)&ks[ntg * 16 + col][quad * 8];
            s16x8 b1 = *(const s16x8*)&ks[ntg * 16 + col][32 + quad * 8];
            f32x4 acc = {0.f, 0.f, 0.f, 0.f};
            acc = __builtin_amdgcn_mfma_f32_16x16x32_bf16(a0, b0, acc, 0, 0, 0);
            acc = __builtin_amdgcn_mfma_f32_16x16x32_bf16(a1, b1, acc, 0, 0, 0);
#pragma unroll
            for (int r = 0; r < 4; r++) {
                int lq = wr * 16 + quad * 4 + r;
                int kk = ntg * 16 + col;
                float x = bf2f(xs[lq][kk]);
                float ang = PIf * x;
                float s1 = __sinf(ang), c1 = __cosf(ang);
                float s2 = 2.f * s1 * c1, c2 = 1.f - 2.f * s1 * s1;
                float s3 = s1 * c2 + c1 * s2, c3 = c1 * c2 - s1 * s2;
                float s5 = s3 * c2 + c3 * s2, c5 = c3 * c2 - s3 * s2;
                float s4 = 2.f * s2 * c2, c4 = 1.f - 2.f * s2 * s2;
                float s9 = s5 * c4 + c5 * s4, c9 = c5 * c4 - s5 * s4;
                float dot = cf[0 * 4 + r] * x + cf[1 * 4 + r] * (-0.5f * x * x)
                          + cf[2 * 4 + r] * s1 + cf[3 * 4 + r] * c1
                          + cf[4 * 4 + r] * s3 + cf[5 * 4 + r] * c3
                          + cf[6 * 4 + r] * s5 + cf[7 * 4 + r] * c5
                          + cf[8 * 4 + r] * s9 + cf[9 * 4 + r] * c9;
                float logit = acc[r] * 0.125f + dot;
                float p = __expf(logit);
                size_t idx = abase + (size_t)lq * 2048 + k0 + kk;
                u16 pb = f2bf(p);
                if constexpr (F32S) p32[idx] = p;
                else                p16[idx] = pb;
                s_l[r] += p;
                xs[lq][kk] = pb;  // in-place LDS transpose source for PV
            }
        }
        // PV on this wave's k-half of the 128-chunk (wave-private xs sub-block)
#pragma unroll
        for (int kc2 = 0; kc2 < 2; kc2++) {
            int kc = wc * 2 + kc2;
            s16x8 af = *(const s16x8*)&xs[wr * 16 + col][kc * 32 + quad * 8];
#pragma unroll
            for (int nt = 0; nt < 4; nt++) {
                uint4 bv4 = *(const uint4*)&vb0[(size_t)nt * 16 * 2048 + k0 + kc * 32];
                accv[nt] = __builtin_amdgcn_mfma_f32_16x16x32_bf16(af, __builtin_bit_cast(s16x8, bv4), accv[nt], 0, 0, 0);
            }
        }
    }

    // partial row sums across the 16 lanes of each quad
    float sred[4];
#pragma unroll
    for (int r = 0; r < 4; r++) {
        float s = s_l[r];
#pragma unroll
        for (int off = 1; off < 16; off <<= 1) s += __shfl_xor(s, off);
        sred[r] = s;
    }

    // cross-wave (wc) combine through reclaimed LDS
    __syncthreads();
    float* red  = (float*)&ks[0][0];  // [4][64][16] = 16 KB (ks is 18 KB)
    float* psum = (float*)&xs[0][0];  // [64] partial sums from wc==1
    if (wc == 1) {
#pragma unroll
        for (int nt = 0; nt < 4; nt++)
#pragma unroll
            for (int r = 0; r < 4; r++)
                red[(wr * 64 + lane) * 16 + nt * 4 + r] = accv[nt][r];
        if (col == 0) {
#pragma unroll
            for (int r = 0; r < 4; r++) psum[wr * 16 + quad * 4 + r] = sred[r];
        }
    }
    __syncthreads();
    if (wc == 0) {
        float inv_r[4];
#pragma unroll
        for (int r = 0; r < 4; r++)
            inv_r[r] = 1.f / (sred[r] + psum[wr * 16 + quad * 4 + r]);
        if (col == 0) {
#pragma unroll
            for (int r = 0; r < 4; r++)
                invb[bh * 2048 + q0 + wr * 16 + quad * 4 + r] = inv_r[r];
        }
#pragma unroll
        for (int nt = 0; nt < 4; nt++)
#pragma unroll
            for (int r = 0; r < 4; r++) {
                float vsum = accv[nt][r] + red[(wr * 64 + lane) * 16 + nt * 4 + r];
                int q = q0 + wr * 16 + quad * 4 + r;
                int d = h * 64 + nt * 16 + col;
                ctx[((size_t)(b * 2048 + q)) * 512 + d] = f2bf(vsum * inv_r[r]);
            }
    }
}

// ---------------------------------------------------------------------------
// normalize p~ -> attn output, one launch. One block per attention row.
// flag==0: bf16 in-place on attnH. flag==1 & BIG: pbuf -> fp32 attnF.
// flag==1 & !BIG: fp32 in-place on attnF.
// ---------------------------------------------------------------------------
template <int BIG>
__global__ __launch_bounds__(256) void knorm(u16* __restrict__ attnH, const u16* __restrict__ pbuf,
                                             float* __restrict__ attnF,
                                             const float* __restrict__ invb, const int* __restrict__ flag) {
    int fl = *flag;
    int row = blockIdx.x;  // 0..32767 = bh*2048 + q
    float inv = invb[row];
    size_t base = (size_t)row * 2048 + threadIdx.x * 8;
    if (fl == 0) {
        uint4 vv = *(const uint4*)&attnH[base];
        unsigned a[4] = {vv.x, vv.y, vv.z, vv.w};
#pragma unroll
        for (int i = 0; i < 4; i++) {
            float lo = b2f_lo(a[i]) * inv;
            float hi = b2f_hi(a[i]) * inv;
            a[i] = ((unsigned)f2bf(hi) << 16) | (unsigned)f2bf(lo);
        }
        uint4 o; o.x = a[0]; o.y = a[1]; o.z = a[2]; o.w = a[3];
        *(uint4*)&attnH[base] = o;
    } else if constexpr (BIG) {
        uint4 vv = *(const uint4*)&pbuf[base];
        unsigned a[4] = {vv.x, vv.y, vv.z, vv.w};
        float4 o0, o1;
        o0.x = b2f_lo(a[0]) * inv; o0.y = b2f_hi(a[0]) * inv;
        o0.z = b2f_lo(a[1]) * inv; o0.w = b2f_hi(a[1]) * inv;
        o1.x = b2f_lo(a[2]) * inv; o1.y = b2f_hi(a[2]) * inv;
        o1.z = b2f_lo(a[3]) * inv; o1.w = b2f_hi(a[3]) * inv;
        *(float4*)&attnF[base] = o0;
        *(float4*)&attnF[base + 4] = o1;
    } else {
        float4 v0 = *(const float4*)&attnF[base];
        float4 v1 = *(const float4*)&attnF[base + 4];
        v0.x *= inv; v0.y *= inv; v0.z *= inv; v0.w *= inv;
        v1.x *= inv; v1.y *= inv; v1.z *= inv; v1.w *= inv;
        *(float4*)&attnF[base] = v0;
        *(float4*)&attnF[base + 4] = v1;
    }
}

// ---------------------------------------------------------------------------
// launch
// ---------------------------------------------------------------------------
extern "C" void kernel_launch(void* const* d_in, const int* in_sizes, int n_in,
                              void* d_out, int out_size, void* d_ws, size_t ws_size,
                              hipStream_t stream) {
    const void* q  = d_in[0];
    const void* k  = d_in[1];
    const void* v  = d_in[2];
    const void* xd = d_in[3];
    const void* Wq = d_in[4];
    const void* bq = d_in[5];
    const void* Wk = d_in[6];
    const void* bk = d_in[7];
    const void* Wv = d_in[8];
    const void* bv = d_in[9];
    const void* Wc = d_in[10];
    const void* bc = d_in[11];
    const void* Wo = d_in[12];
    const void* bo = d_in[13];

    char* ws = (char*)d_ws;
    int*   flag = (int*)(ws + OFF_FLAG);
    u16*   WT   = (u16*)(ws + OFF_WT);
    u16*   WcT  = (u16*)(ws + OFF_WCT);
    u16*   qb   = (u16*)(ws + OFF_QB);
    u16*   kb   = (u16*)(ws + OFF_KB);
    u16*   vb   = (u16*)(ws + OFF_VB);
    u16*   xb   = (u16*)(ws + OFF_XB);
    u16*   qp   = (u16*)(ws + OFF_QP);
    u16*   kp   = (u16*)(ws + OFF_KP);
    u16*   vp   = (u16*)(ws + OFF_VP);
    u16*   vT   = (u16*)(ws + OFF_VT);
    float* coef = (float*)(ws + OFF_COEF);
    u16*   ctx  = (u16*)(ws + OFF_CTX);
    u16*   bB   = (u16*)(ws + OFF_BIAS);
    float* invb = (float*)(ws + OFF_INV);
    u16*   pbuf = (u16*)(ws + OFF_PBUF);

    u16*   outH  = (u16*)d_out;
    u16*   attnH = outH + 2097152;
    float* outF  = (float*)d_out;
    float* attnF = outF + 2097152;

    // bf16 p~ staging buffer needs 134 MB of ws; fall back to fp32-in-place if absent
    bool big = ws_size >= (size_t)OFF_PBUF + 134217728ull;

    kdetect<<<1, 64, 0, stream>>>((const u32*)Wq, flag);
    kcvt3<<<dim3(2048, 3), 256, 0, stream>>>(q, k, v, qb, flag);
    kcvt<<<8192, 256, 0, stream>>>(xd, xb, 8388608, flag);
    kbias<<<1, 512, 0, stream>>>(bq, bk, bv, bo, bc, bB, flag);
    ktrans512<<<dim3(16, 16, 4), dim3(32, 32), 0, stream>>>(Wq, Wk, Wv, Wo, WT, flag);
    kwct<<<80, 64, 0, stream>>>(Wc, WcT, flag);
    kgemm<<<dim3(8, 64), 256, 0, stream>>>(qb, WT, bB, qp);
    kgemm<<<dim3(8, 64), 256, 0, stream>>>(kb, WT + 262144, bB + 512, kp);
    kgemm<<<dim3(8, 64), 256, 0, stream>>>(vb, WT + 524288, bB + 1024, vp);
    kvtrans<<<dim3(16, 64, 2), dim3(32, 32), 0, stream>>>(vp, vT);
    kcoef<<<64, 256, 0, stream>>>(qp, WcT, bB + 2048, coef);

    kattn_t<0><<<dim3(32, 16), 512, 0, stream>>>(qp, kp, vT, xb, coef, attnH, pbuf, attnF,
                                                 ctx, invb, flag, (int)big);
    if (!big)
        kattn_t<1><<<dim3(32, 16), 512, 0, stream>>>(qp, kp, vT, xb, coef, attnH, pbuf, attnF,
                                                     ctx, invb, flag, 0);

    if (big) knorm<1><<<32768, 256, 0, stream>>>(attnH, pbuf, attnF, invb, flag);
    else     knorm<0><<<32768, 256, 0, stream>>>(attnH, pbuf, attnF, invb, flag);

    kgemm_final<<<dim3(8, 64), 256, 0, stream>>>(ctx, WT + 786432, bB + 1536, outH, outF, flag);
}

// Round 8
// 619.758 us; speedup vs baseline: 1.3793x; 1.0293x over previous
//
#include <hip/hip_runtime.h>

typedef unsigned short u16;
typedef unsigned int u32;
typedef __attribute__((ext_vector_type(8))) short s16x8;
typedef __attribute__((ext_vector_type(4))) float f32x4;

#define PIf 3.14159265358979323846f

__device__ __forceinline__ float bf2f(u16 u) {
    unsigned v = (unsigned)u << 16;
    return __builtin_bit_cast(float, v);
}
__device__ __forceinline__ u16 f2bf(float f) {
    unsigned u = __builtin_bit_cast(unsigned, f);
    u += 0x7fffu + ((u >> 16) & 1u);
    return (u16)(u >> 16);
}
__device__ __forceinline__ float b2f_lo(unsigned w) { return __builtin_bit_cast(float, w << 16); }
__device__ __forceinline__ float b2f_hi(unsigned w) { return __builtin_bit_cast(float, w & 0xffff0000u); }

// ws layout (bytes)
#define OFF_FLAG 0
#define OFF_WT   256
#define OFF_WCT  2097408
#define OFF_QB   2179328
#define OFF_KB   6373632
#define OFF_VB   10567936
#define OFF_XB   14762240
#define OFF_QP   31539456
#define OFF_KP   35733760
#define OFF_VP   39928064
#define OFF_VT   44122368
#define OFF_COEF 48316672
#define OFF_CTX  49627392
#define OFF_BIAS 53821696
#define OFF_INV  53829888
#define OFF_PBUF 53960960

// ---------------------------------------------------------------------------
// dtype probe: fp32 N(0,0.02) words all have |v| < 0.5; bf16-pair words
// reinterpret to ~2^100 magnitudes. flag = 1 -> inputs/outputs are fp32.
// ---------------------------------------------------------------------------
__global__ void kdetect(const u32* __restrict__ wq, int* __restrict__ flag) {
    int lane = threadIdx.x;
    float v = fabsf(__builtin_bit_cast(float, wq[lane]));
    bool smallv = (v > 1e-30f) && (v < 0.5f);
    unsigned long long m = __ballot(smallv);
    if (lane == 0) *flag = (__popcll(m) >= 32) ? 1 : 0;
}

// ---------------------------------------------------------------------------
// convert (or copy) q,k,v (blockIdx.y selects) into contiguous bf16 ws buffers
// ---------------------------------------------------------------------------
__global__ void kcvt3(const void* __restrict__ s0, const void* __restrict__ s1,
                      const void* __restrict__ s2, u16* __restrict__ dst,
                      const int* __restrict__ flag) {
    const void* srcs[3] = {s0, s1, s2};
    const void* src = srcs[blockIdx.y];
    u16* d = dst + (size_t)blockIdx.y * 2097152;
    int i = (blockIdx.x * 256 + threadIdx.x) * 4;
    if (*flag) {
        float4 f = *(const float4*)((const float*)src + i);
        u16 r[4] = {f2bf(f.x), f2bf(f.y), f2bf(f.z), f2bf(f.w)};
        *(uint2*)(d + i) = *(const uint2*)r;
    } else {
        *(uint2*)(d + i) = *(const uint2*)((const u16*)src + i);
    }
}

__global__ void kcvt(const void* __restrict__ src, u16* __restrict__ dst, int n,
                     const int* __restrict__ flag) {
    int i = (blockIdx.x * 256 + threadIdx.x) * 4;
    if (i >= n) return;
    if (*flag) {
        float4 f = *(const float4*)((const float*)src + i);
        u16 r[4] = {f2bf(f.x), f2bf(f.y), f2bf(f.z), f2bf(f.w)};
        *(uint2*)(dst + i) = *(const uint2*)r;
    } else {
        *(uint2*)(dst + i) = *(const uint2*)((const u16*)src + i);
    }
}

// biases: [bq 512][bk 512][bv 512][bo 512][bcoef 80] -> bf16 ws
__global__ void kbias(const void* __restrict__ bq, const void* __restrict__ bk,
                      const void* __restrict__ bv, const void* __restrict__ bo,
                      const void* __restrict__ bc, u16* __restrict__ dst,
                      const int* __restrict__ flag) {
    int t = threadIdx.x;  // 512
    bool f = *flag != 0;
    dst[t]        = f ? f2bf(((const float*)bq)[t]) : ((const u16*)bq)[t];
    dst[512 + t]  = f ? f2bf(((const float*)bk)[t]) : ((const u16*)bk)[t];
    dst[1024 + t] = f ? f2bf(((const float*)bv)[t]) : ((const u16*)bv)[t];
    dst[1536 + t] = f ? f2bf(((const float*)bo)[t]) : ((const u16*)bo)[t];
    if (t < 80)
        dst[2048 + t] = f ? f2bf(((const float*)bc)[t]) : ((const u16*)bc)[t];
}

// ---------------------------------------------------------------------------
// transpose the four 512x512 weight matrices (W[k][n] -> WT[n][k]), bf16 out
// ---------------------------------------------------------------------------
__global__ void ktrans512(const void* __restrict__ wq, const void* __restrict__ wk,
                          const void* __restrict__ wv, const void* __restrict__ wo,
                          u16* __restrict__ dst, const int* __restrict__ flag) {
    __shared__ u16 t[32][33];
    const void* srcs[4] = {wq, wk, wv, wo};
    const void* src = srcs[blockIdx.z];
    bool f = *flag != 0;
    u16* d = dst + (size_t)blockIdx.z * 512 * 512;
    int x0 = blockIdx.x * 32, y0 = blockIdx.y * 32;
    size_t si = (size_t)(y0 + threadIdx.y) * 512 + x0 + threadIdx.x;
    t[threadIdx.y][threadIdx.x] = f ? f2bf(((const float*)src)[si]) : ((const u16*)src)[si];
    __syncthreads();
    d[(size_t)(x0 + threadIdx.y) * 512 + y0 + threadIdx.x] = t[threadIdx.x][threadIdx.y];
}

// Wcoef (10,512,8) -> WcT[(n*8+h)][d], bf16
__global__ void kwct(const void* __restrict__ wc, u16* __restrict__ dst,
                     const int* __restrict__ flag) {
    int nh = blockIdx.x;  // 0..79
    int n = nh >> 3, h = nh & 7;
    bool f = *flag != 0;
    for (int d = threadIdx.x; d < 512; d += 64) {
        size_t si = ((size_t)n * 512 + d) * 8 + h;
        dst[nh * 512 + d] = f ? f2bf(((const float*)wc)[si]) : ((const u16*)wc)[si];
    }
}

// ---------------------------------------------------------------------------
// batched projection GEMM: z = 0,1,2 -> qp, kp, vT(transposed write).
// out[4096][512] = A[4096][512] @ BT^T + bias (all bf16, MFMA)
// ---------------------------------------------------------------------------
__global__ __launch_bounds__(256) void kgemm3(const u16* __restrict__ qkv, const u16* __restrict__ WT,
                                              const u16* __restrict__ bias, u16* __restrict__ qp,
                                              u16* __restrict__ kpj, u16* __restrict__ vT) {
    int z = blockIdx.z;
    const u16* A  = qkv + (size_t)z * 2097152;
    const u16* BT = WT + (size_t)z * 262144;
    const u16* bs = bias + z * 512;
    __shared__ u16 As[64][40];
    __shared__ u16 Bs[64][40];
    int tid = threadIdx.x;
    int w = tid >> 6, lane = tid & 63, quad = lane >> 4, col = lane & 15;
    int m0 = blockIdx.y * 64, n0 = blockIdx.x * 64;
    int wm = (w >> 1) * 32, wn = (w & 1) * 32;
    int sr = tid >> 2, sc = tid & 3;
    f32x4 acc[2][2] = {};
    for (int kt = 0; kt < 512; kt += 32) {
        __syncthreads();
        *(uint4*)&As[sr][sc * 8] = *(const uint4*)&A[(size_t)(m0 + sr) * 512 + kt + sc * 8];
        *(uint4*)&Bs[sr][sc * 8] = *(const uint4*)&BT[(size_t)(n0 + sr) * 512 + kt + sc * 8];
        __syncthreads();
        s16x8 a[2], b[2];
        a[0] = *(const s16x8*)&As[wm + col][quad * 8];
        a[1] = *(const s16x8*)&As[wm + 16 + col][quad * 8];
        b[0] = *(const s16x8*)&Bs[wn + col][quad * 8];
        b[1] = *(const s16x8*)&Bs[wn + 16 + col][quad * 8];
#pragma unroll
        for (int mi = 0; mi < 2; mi++)
#pragma unroll
            for (int ni = 0; ni < 2; ni++)
                acc[mi][ni] = __builtin_amdgcn_mfma_f32_16x16x32_bf16(a[mi], b[ni], acc[mi][ni], 0, 0, 0);
    }
    if (z < 2) {
        u16* out = z ? kpj : qp;
#pragma unroll
        for (int mi = 0; mi < 2; mi++)
#pragma unroll
            for (int ni = 0; ni < 2; ni++) {
                int n = n0 + wn + ni * 16 + col;
                float bv = bf2f(bs[n]);
#pragma unroll
                for (int r = 0; r < 4; r++) {
                    int m = m0 + wm + mi * 16 + quad * 4 + r;
                    out[(size_t)m * 512 + n] = f2bf(acc[mi][ni][r] + bv);
                }
            }
    } else {
        // transposed packed write: vT[b][d][s], 4 consecutive s per lane
#pragma unroll
        for (int mi = 0; mi < 2; mi++)
#pragma unroll
            for (int ni = 0; ni < 2; ni++) {
                int n = n0 + wn + ni * 16 + col;
                float bv = bf2f(bs[n]);
                int m = m0 + wm + mi * 16 + quad * 4;
                int bb = m >> 11, s = m & 2047;
                u16 pk4[4];
#pragma unroll
                for (int r = 0; r < 4; r++) pk4[r] = f2bf(acc[mi][ni][r] + bv);
                *(uint2*)&vT[((size_t)(bb * 512 + n)) * 2048 + s] = *(const uint2*)pk4;
            }
    }
}

// final GEMM: same compute, runtime dtype-selected store into d_out (1 launch)
__global__ __launch_bounds__(256) void kgemm_final(const u16* __restrict__ A, const u16* __restrict__ BT,
                                                   const u16* __restrict__ bias, u16* __restrict__ outH,
                                                   float* __restrict__ outF, const int* __restrict__ flag) {
    bool f32o = *flag != 0;
    __shared__ u16 As[64][40];
    __shared__ u16 Bs[64][40];
    int tid = threadIdx.x;
    int w = tid >> 6, lane = tid & 63, quad = lane >> 4, col = lane & 15;
    int m0 = blockIdx.y * 64, n0 = blockIdx.x * 64;
    int wm = (w >> 1) * 32, wn = (w & 1) * 32;
    int sr = tid >> 2, sc = tid & 3;
    f32x4 acc[2][2] = {};
    for (int kt = 0; kt < 512; kt += 32) {
        __syncthreads();
        *(uint4*)&As[sr][sc * 8] = *(const uint4*)&A[(size_t)(m0 + sr) * 512 + kt + sc * 8];
        *(uint4*)&Bs[sr][sc * 8] = *(const uint4*)&BT[(size_t)(n0 + sr) * 512 + kt + sc * 8];
        __syncthreads();
        s16x8 a[2], b[2];
        a[0] = *(const s16x8*)&As[wm + col][quad * 8];
        a[1] = *(const s16x8*)&As[wm + 16 + col][quad * 8];
        b[0] = *(const s16x8*)&Bs[wn + col][quad * 8];
        b[1] = *(const s16x8*)&Bs[wn + 16 + col][quad * 8];
#pragma unroll
        for (int mi = 0; mi < 2; mi++)
#pragma unroll
            for (int ni = 0; ni < 2; ni++)
                acc[mi][ni] = __builtin_amdgcn_mfma_f32_16x16x32_bf16(a[mi], b[ni], acc[mi][ni], 0, 0, 0);
    }
#pragma unroll
    for (int mi = 0; mi < 2; mi++)
#pragma unroll
        for (int ni = 0; ni < 2; ni++) {
            int n = n0 + wn + ni * 16 + col;
            float bv = bf2f(bias[n]);
#pragma unroll
            for (int r = 0; r < 4; r++) {
                int m = m0 + wm + mi * 16 + quad * 4 + r;
                float val = acc[mi][ni][r] + bv;
                if (f32o) outF[(size_t)m * 512 + n] = val;
                else      outH[(size_t)m * 512 + n] = f2bf(val);
            }
        }
}

// ---------------------------------------------------------------------------
// coefs[(b*8+h)*10+n][s] (fp32, pre-scaled by 0.0125, abs on n==1)
// MFMA version: out[4096][80] = qp @ WcT^T, one 64-row tile per block.
// ---------------------------------------------------------------------------
__global__ __launch_bounds__(256) void kcoef(const u16* __restrict__ qp, const u16* __restrict__ wct,
                                             const u16* __restrict__ bc, float* __restrict__ cout) {
    __shared__ u16 As[64][40];
    int tid = threadIdx.x;
    int w = tid >> 6, lane = tid & 63, quad = lane >> 4, col = lane & 15;
    int m0 = blockIdx.x * 64;
    int sr = tid >> 2, sc = tid & 3;
    f32x4 acc[5] = {};
    for (int kt = 0; kt < 512; kt += 32) {
        __syncthreads();
        *(uint4*)&As[sr][sc * 8] = *(const uint4*)&qp[(size_t)(m0 + sr) * 512 + kt + sc * 8];
        __syncthreads();
        s16x8 a = *(const s16x8*)&As[w * 16 + col][quad * 8];
#pragma unroll
        for (int nt = 0; nt < 5; nt++) {
            uint4 bv4 = *(const uint4*)&wct[(size_t)(nt * 16 + col) * 512 + kt + quad * 8];
            acc[nt] = __builtin_amdgcn_mfma_f32_16x16x32_bf16(a, __builtin_bit_cast(s16x8, bv4), acc[nt], 0, 0, 0);
        }
    }
    int m = m0 + w * 16 + quad * 4;
    int b = m >> 11, s = m & 2047;
#pragma unroll
    for (int nt = 0; nt < 5; nt++) {
        int nh = nt * 16 + col, n = nh >> 3, h = nh & 7;
        float bvv = bf2f(bc[nh]);
        float4 o;
        float tmp[4];
#pragma unroll
        for (int r = 0; r < 4; r++) {
            float c = acc[nt][r] + bvv;
            if (n == 1) c = fabsf(c);
            tmp[r] = c * 0.0125f;  // 0.1 * (1/sqrt(64))
        }
        o.x = tmp[0]; o.y = tmp[1]; o.z = tmp[2]; o.w = tmp[3];
        *(float4*)&cout[((size_t)((b * 8 + h) * 10 + n)) * 2048 + s] = o;
    }
}

// ---------------------------------------------------------------------------
// fused attention sweep, 8 waves (512 thr), register-prefetch double buffer:
//   C: issue global loads (chunk c+1) -> VGPRs   (latency hides under A/B)
//   A: QK^T MFMA + basis + exp -> p~ into xs in place (free transpose)
//   B: PV MFMA from wave-private xs sub-block
//   barrier1
//   D: vectorized p~ store xs -> global (dwordx4; same byte-partition as E)
//   E: ds_write staged regs -> ks/xs (chunk c+1)
//   barrier2
// Cross-wave combine of partial PV accumulators + row sums via reclaimed LDS.
// F32S=0: bf16 p~ -> attnH (flag 0) or pbuf (flag 1 & big ws).
// F32S=1: fp32 p~ -> attnF (flag 1, small-ws fallback; bf16-quantized).
// ---------------------------------------------------------------------------
template <int F32S>
__global__ __launch_bounds__(512) void kattn_t(const u16* __restrict__ qp, const u16* __restrict__ kp,
                                               const u16* __restrict__ vT, const u16* __restrict__ xd,
                                               const float* __restrict__ coef,
                                               u16* __restrict__ attnH, u16* __restrict__ pbuf,
                                               float* __restrict__ p32,
                                               u16* __restrict__ ctx, float* __restrict__ invb,
                                               const int* __restrict__ flag, int big) {
    int fl = *flag;
    if constexpr (F32S) { if (fl != 1) return; }        // only small-ws fp32 path
    else                { if (fl && !big) return; }      // fp32 handled by F32S=1
    u16* p16 = fl ? pbuf : attnH;

    __shared__ u16 qs[64][72];
    __shared__ u16 ks[128][72];
    __shared__ u16 xs[64][136];
    __shared__ float cfl[10][64];

    int tid = threadIdx.x;
    int lane = tid & 63, quad = lane >> 4, col = lane & 15;
    int w = tid >> 6;
    int wr = w & 3, wc = w >> 2;
    int qt = blockIdx.x, bh = blockIdx.y;
    int b = bh >> 3, h = bh & 7;
    int q0 = qt * 64;

    // staging thread mappings (E and D use the SAME xs byte-partition)
    int kr = tid >> 2, hf = tid & 3;   // ks: row kr, 16-col group hf
    int qr = tid >> 3, qu = tid & 7;   // xs: row qr, 16-col group qu

    const u16* ksrc0 = kp + ((size_t)(b * 2048 + kr)) * 512 + h * 64 + hf * 16;
    const u16* xsrc0 = xd + ((size_t)(b * 2048 + q0 + qr)) * 2048 + qu * 16;

    // prefetch chunk 0 into regs
    uint4 kg0 = *(const uint4*)&ksrc0[0];
    uint4 kg1 = *(const uint4*)&ksrc0[8];
    uint4 xg0 = *(const uint4*)&xsrc0[0];
    uint4 xg1 = *(const uint4*)&xsrc0[8];

    // qs + cfl staging (overlaps the prefetch latency)
    {
        int r = tid >> 3, c8 = tid & 7;
        const u16* src = qp + ((size_t)(b * 2048 + q0 + r)) * 512 + h * 64 + c8 * 8;
        *(uint4*)&qs[r][c8 * 8] = *(const uint4*)src;
    }
    if (tid < 160) {
        int n = tid >> 4, i = tid & 15;
        *(float4*)&cfl[n][i * 4] = *(const float4*)&coef[((size_t)(bh * 10 + n)) * 2048 + q0 + i * 4];
    }
    // write staged chunk 0 (compiler waits vmcnt for kg/xg)
    *(uint4*)&ks[kr][hf * 16]     = kg0;
    *(uint4*)&ks[kr][hf * 16 + 8] = kg1;
    *(uint4*)&xs[qr][qu * 16]     = xg0;
    *(uint4*)&xs[qr][qu * 16 + 8] = xg1;
    __syncthreads();

    float cf[40];
#pragma unroll
    for (int n = 0; n < 10; n++)
#pragma unroll
        for (int r = 0; r < 4; r++) cf[n * 4 + r] = cfl[n][wr * 16 + quad * 4 + r];

    s16x8 a0 = *(const s16x8*)&qs[wr * 16 + col][quad * 8];
    s16x8 a1 = *(const s16x8*)&qs[wr * 16 + col][32 + quad * 8];

    float s_l[4] = {0.f, 0.f, 0.f, 0.f};
    f32x4 accv[4] = {};

    size_t abase = ((size_t)(bh * 2048 + q0)) * 2048;
    const u16* vb0 = vT + ((size_t)(b * 512 + h * 64 + col)) * 2048 + quad * 8;

    for (int c = 0; c < 16; c++) {
        int k0 = c * 128;
        // C: issue next-chunk prefetch (no wait; hides under A/B)
        if (c < 15) {
            const u16* ksrc = ksrc0 + (size_t)(k0 + 128) * 512;
            const u16* xsrc = xsrc0 + k0 + 128;
            kg0 = *(const uint4*)&ksrc[0];
            kg1 = *(const uint4*)&ksrc[8];
            xg0 = *(const uint4*)&xsrc[0];
            xg1 = *(const uint4*)&xsrc[8];
        }
        // A: QK^T + basis + exp -> p~ in xs (in-place transpose), s_l accum
#pragma unroll
        for (int nt = 0; nt < 4; nt++) {
            int ntg = wc * 4 + nt;
            s16x8 b0 = *(const s16x8*)&ks[ntg * 16 + col][quad * 8];
            s16x8 b1 = *(const s16x8*)&ks[ntg * 16 + col][32 + quad * 8];
            f32x4 acc = {0.f, 0.f, 0.f, 0.f};
            acc = __builtin_amdgcn_mfma_f32_16x16x32_bf16(a0, b0, acc, 0, 0, 0);
            acc = __builtin_amdgcn_mfma_f32_16x16x32_bf16(a1, b1, acc, 0, 0, 0);
#pragma unroll
            for (int r = 0; r < 4; r++) {
                int lq = wr * 16 + quad * 4 + r;
                int kk = ntg * 16 + col;
                float x = bf2f(xs[lq][kk]);
                float ang = PIf * x;
                float s1 = __sinf(ang), c1 = __cosf(ang);
                float s2 = 2.f * s1 * c1, c2 = 1.f - 2.f * s1 * s1;
                float s3 = s1 * c2 + c1 * s2, c3 = c1 * c2 - s1 * s2;
                float s5 = s3 * c2 + c3 * s2, c5 = c3 * c2 - s3 * s2;
                float s4 = 2.f * s2 * c2, c4 = 1.f - 2.f * s2 * s2;
                float s9 = s5 * c4 + c5 * s4, c9 = c5 * c4 - s5 * s4;
                float dot = cf[0 * 4 + r] * x + cf[1 * 4 + r] * (-0.5f * x * x)
                          + cf[2 * 4 + r] * s1 + cf[3 * 4 + r] * c1
                          + cf[4 * 4 + r] * s3 + cf[5 * 4 + r] * c3
                          + cf[6 * 4 + r] * s5 + cf[7 * 4 + r] * c5
                          + cf[8 * 4 + r] * s9 + cf[9 * 4 + r] * c9;
                float logit = acc[r] * 0.125f + dot;
                float p = __expf(logit);
                s_l[r] += p;
                xs[lq][kk] = f2bf(p);  // in-place LDS transpose source for PV + D
            }
        }
        // B: PV on this wave's k-half (wave-private xs sub-block)
#pragma unroll
        for (int kc2 = 0; kc2 < 2; kc2++) {
            int kc = wc * 2 + kc2;
            s16x8 af = *(const s16x8*)&xs[wr * 16 + col][kc * 32 + quad * 8];
#pragma unroll
            for (int nt = 0; nt < 4; nt++) {
                uint4 bv4 = *(const uint4*)&vb0[(size_t)nt * 16 * 2048 + k0 + kc * 32];
                accv[nt] = __builtin_amdgcn_mfma_f32_16x16x32_bf16(af, __builtin_bit_cast(s16x8, bv4), accv[nt], 0, 0, 0);
            }
        }
        __syncthreads();  // barrier1: all p~ of chunk c in xs
        // D: vectorized p~ store (reads exactly the bytes E will overwrite)
        {
            size_t gbase = abase + (size_t)qr * 2048 + k0 + qu * 16;
            uint4 v0 = *(const uint4*)&xs[qr][qu * 16];
            uint4 v1 = *(const uint4*)&xs[qr][qu * 16 + 8];
            if constexpr (F32S) {
                unsigned aa[8] = {v0.x, v0.y, v0.z, v0.w, v1.x, v1.y, v1.z, v1.w};
                float* dst = p32 + gbase;
#pragma unroll
                for (int j = 0; j < 4; j++) {
                    float4 o;
                    o.x = b2f_lo(aa[2 * j]);     o.y = b2f_hi(aa[2 * j]);
                    o.z = b2f_lo(aa[2 * j + 1]); o.w = b2f_hi(aa[2 * j + 1]);
                    *(float4*)&dst[j * 4] = o;
                }
            } else {
                u16* dst = p16 + gbase;
                *(uint4*)&dst[0] = v0;
                *(uint4*)&dst[8] = v1;
            }
        }
        // E: write staged next chunk (same per-thread xs bytes as D just read)
        if (c < 15) {
            *(uint4*)&ks[kr][hf * 16]     = kg0;
            *(uint4*)&ks[kr][hf * 16 + 8] = kg1;
            *(uint4*)&xs[qr][qu * 16]     = xg0;
            *(uint4*)&xs[qr][qu * 16 + 8] = xg1;
        }
        __syncthreads();  // barrier2
    }

    // partial row sums across the 16 lanes of each quad
    float sred[4];
#pragma unroll
    for (int r = 0; r < 4; r++) {
        float s = s_l[r];
#pragma unroll
        for (int off = 1; off < 16; off <<= 1) s += __shfl_xor(s, off);
        sred[r] = s;
    }

    // cross-wave (wc) combine through reclaimed LDS (loop exits after barrier2)
    float* red  = (float*)&ks[0][0];  // [4][64][16] = 16 KB (ks is 18 KB)
    float* psum = (float*)&xs[0][0];  // [64] partial sums from wc==1
    if (wc == 1) {
#pragma unroll
        for (int nt = 0; nt < 4; nt++)
#pragma unroll
            for (int r = 0; r < 4; r++)
                red[(wr * 64 + lane) * 16 + nt * 4 + r] = accv[nt][r];
        if (col == 0) {
#pragma unroll
            for (int r = 0; r < 4; r++) psum[wr * 16 + quad * 4 + r] = sred[r];
        }
    }
    __syncthreads();
    if (wc == 0) {
        float inv_r[4];
#pragma unroll
        for (int r = 0; r < 4; r++)
            inv_r[r] = 1.f / (sred[r] + psum[wr * 16 + quad * 4 + r]);
        if (col == 0) {
#pragma unroll
            for (int r = 0; r < 4; r++)
                invb[bh * 2048 + q0 + wr * 16 + quad * 4 + r] = inv_r[r];
        }
#pragma unroll
        for (int nt = 0; nt < 4; nt++)
#pragma unroll
            for (int r = 0; r < 4; r++) {
                float vsum = accv[nt][r] + red[(wr * 64 + lane) * 16 + nt * 4 + r];
                int q = q0 + wr * 16 + quad * 4 + r;
                int d = h * 64 + nt * 16 + col;
                ctx[((size_t)(b * 2048 + q)) * 512 + d] = f2bf(vsum * inv_r[r]);
            }
    }
}

// ---------------------------------------------------------------------------
// normalize p~ -> attn output, one launch. One block per attention row.
// flag==0: bf16 in-place on attnH. flag==1 & BIG: pbuf -> fp32 attnF.
// flag==1 & !BIG: fp32 in-place on attnF.
// ---------------------------------------------------------------------------
template <int BIG>
__global__ __launch_bounds__(256) void knorm(u16* __restrict__ attnH, const u16* __restrict__ pbuf,
                                             float* __restrict__ attnF,
                                             const float* __restrict__ invb, const int* __restrict__ flag) {
    int fl = *flag;
    int row = blockIdx.x;  // 0..32767 = bh*2048 + q
    float inv = invb[row];
    size_t base = (size_t)row * 2048 + threadIdx.x * 8;
    if (fl == 0) {
        uint4 vv = *(const uint4*)&attnH[base];
        unsigned a[4] = {vv.x, vv.y, vv.z, vv.w};
#pragma unroll
        for (int i = 0; i < 4; i++) {
            float lo = b2f_lo(a[i]) * inv;
            float hi = b2f_hi(a[i]) * inv;
            a[i] = ((unsigned)f2bf(hi) << 16) | (unsigned)f2bf(lo);
        }
        uint4 o; o.x = a[0]; o.y = a[1]; o.z = a[2]; o.w = a[3];
        *(uint4*)&attnH[base] = o;
    } else if constexpr (BIG) {
        uint4 vv = *(const uint4*)&pbuf[base];
        unsigned a[4] = {vv.x, vv.y, vv.z, vv.w};
        float4 o0, o1;
        o0.x = b2f_lo(a[0]) * inv; o0.y = b2f_hi(a[0]) * inv;
        o0.z = b2f_lo(a[1]) * inv; o0.w = b2f_hi(a[1]) * inv;
        o1.x = b2f_lo(a[2]) * inv; o1.y = b2f_hi(a[2]) * inv;
        o1.z = b2f_lo(a[3]) * inv; o1.w = b2f_hi(a[3]) * inv;
        *(float4*)&attnF[base] = o0;
        *(float4*)&attnF[base + 4] = o1;
    } else {
        float4 v0 = *(const float4*)&attnF[base];
        float4 v1 = *(const float4*)&attnF[base + 4];
        v0.x *= inv; v0.y *= inv; v0.z *= inv; v0.w *= inv;
        v1.x *= inv; v1.y *= inv; v1.z *= inv; v1.w *= inv;
        *(float4*)&attnF[base] = v0;
        *(float4*)&attnF[base + 4] = v1;
    }
}

// ---------------------------------------------------------------------------
// launch
// ---------------------------------------------------------------------------
extern "C" void kernel_launch(void* const* d_in, const int* in_sizes, int n_in,
                              void* d_out, int out_size, void* d_ws, size_t ws_size,
                              hipStream_t stream) {
    const void* q  = d_in[0];
    const void* k  = d_in[1];
    const void* v  = d_in[2];
    const void* xd = d_in[3];
    const void* Wq = d_in[4];
    const void* bq = d_in[5];
    const void* Wk = d_in[6];
    const void* bk = d_in[7];
    const void* Wv = d_in[8];
    const void* bv = d_in[9];
    const void* Wc = d_in[10];
    const void* bc = d_in[11];
    const void* Wo = d_in[12];
    const void* bo = d_in[13];

    char* ws = (char*)d_ws;
    int*   flag = (int*)(ws + OFF_FLAG);
    u16*   WT   = (u16*)(ws + OFF_WT);
    u16*   WcT  = (u16*)(ws + OFF_WCT);
    u16*   qb   = (u16*)(ws + OFF_QB);
    u16*   xb   = (u16*)(ws + OFF_XB);
    u16*   qp   = (u16*)(ws + OFF_QP);
    u16*   kp   = (u16*)(ws + OFF_KP);
    u16*   vT   = (u16*)(ws + OFF_VT);
    float* coef = (float*)(ws + OFF_COEF);
    u16*   ctx  = (u16*)(ws + OFF_CTX);
    u16*   bB   = (u16*)(ws + OFF_BIAS);
    float* invb = (float*)(ws + OFF_INV);
    u16*   pbuf = (u16*)(ws + OFF_PBUF);

    u16*   outH  = (u16*)d_out;
    u16*   attnH = outH + 2097152;
    float* outF  = (float*)d_out;
    float* attnF = outF + 2097152;

    // bf16 p~ staging buffer needs 134 MB of ws; fall back to fp32-in-place if absent
    bool big = ws_size >= (size_t)OFF_PBUF + 134217728ull;

    kdetect<<<1, 64, 0, stream>>>((const u32*)Wq, flag);
    kcvt3<<<dim3(2048, 3), 256, 0, stream>>>(q, k, v, qb, flag);
    kcvt<<<8192, 256, 0, stream>>>(xd, xb, 8388608, flag);
    kbias<<<1, 512, 0, stream>>>(bq, bk, bv, bo, bc, bB, flag);
    ktrans512<<<dim3(16, 16, 4), dim3(32, 32), 0, stream>>>(Wq, Wk, Wv, Wo, WT, flag);
    kwct<<<80, 64, 0, stream>>>(Wc, WcT, flag);
    kgemm3<<<dim3(8, 64, 3), 256, 0, stream>>>(qb, WT, bB, qp, kp, vT);
    kcoef<<<64, 256, 0, stream>>>(qp, WcT, bB + 2048, coef);

    kattn_t<0><<<dim3(32, 16), 512, 0, stream>>>(qp, kp, vT, xb, coef, attnH, pbuf, attnF,
                                                 ctx, invb, flag, (int)big);
    if (!big)
        kattn_t<1><<<dim3(32, 16), 512, 0, stream>>>(qp, kp, vT, xb, coef, attnH, pbuf, attnF,
                                                     ctx, invb, flag, 0);

    if (big) knorm<1><<<32768, 256, 0, stream>>>(attnH, pbuf, attnF, invb, flag);
    else     knorm<0><<<32768, 256, 0, stream>>>(attnH, pbuf, attnF, invb, flag);

    kgemm_final<<<dim3(8, 64), 256, 0, stream>>>(ctx, WT + 786432, bB + 1536, outH, outF, flag);
}

// Round 9
// 595.350 us; speedup vs baseline: 1.4358x; 1.0410x over previous
//
#include <hip/hip_runtime.h>

typedef unsigned short u16;
typedef unsigned int u32;
typedef __attribute__((ext_vector_type(8))) short s16x8;
typedef __attribute__((ext_vector_type(4))) float f32x4;

#define PIf 3.14159265358979323846f

__device__ __forceinline__ float bf2f(u16 u) {
    unsigned v = (unsigned)u << 16;
    return __builtin_bit_cast(float, v);
}
__device__ __forceinline__ u16 f2bf(float f) {
    unsigned u = __builtin_bit_cast(unsigned, f);
    u += 0x7fffu + ((u >> 16) & 1u);
    return (u16)(u >> 16);
}
__device__ __forceinline__ float b2f_lo(unsigned w) { return __builtin_bit_cast(float, w << 16); }
__device__ __forceinline__ float b2f_hi(unsigned w) { return __builtin_bit_cast(float, w & 0xffff0000u); }

// ws layout (bytes)
#define OFF_FLAG 0
#define OFF_WT   256
#define OFF_WCT  2097408
#define OFF_QB   2179328
#define OFF_KB   6373632
#define OFF_VB   10567936
#define OFF_XB   14762240
#define OFF_QP   31539456
#define OFF_KP   35733760
#define OFF_VP   39928064
#define OFF_VT   44122368
#define OFF_COEF 48316672
#define OFF_CTX  49627392
#define OFF_BIAS 53821696
#define OFF_INV  53829888
#define OFF_PBUF 53960960

// ---------------------------------------------------------------------------
// dtype probe: fp32 N(0,0.02) words all have |v| < 0.5; bf16-pair words
// reinterpret to ~2^100 magnitudes. flag = 1 -> inputs/outputs are fp32.
// ---------------------------------------------------------------------------
__global__ void kdetect(const u32* __restrict__ wq, int* __restrict__ flag) {
    int lane = threadIdx.x;
    float v = fabsf(__builtin_bit_cast(float, wq[lane]));
    bool smallv = (v > 1e-30f) && (v < 0.5f);
    unsigned long long m = __ballot(smallv);
    if (lane == 0) *flag = (__popcll(m) >= 32) ? 1 : 0;
}

// ---------------------------------------------------------------------------
// convert (or copy) q,k,v (blockIdx.y selects) into contiguous bf16 ws buffers
// ---------------------------------------------------------------------------
__global__ void kcvt3(const void* __restrict__ s0, const void* __restrict__ s1,
                      const void* __restrict__ s2, u16* __restrict__ dst,
                      const int* __restrict__ flag) {
    const void* srcs[3] = {s0, s1, s2};
    const void* src = srcs[blockIdx.y];
    u16* d = dst + (size_t)blockIdx.y * 2097152;
    int i = (blockIdx.x * 256 + threadIdx.x) * 4;
    if (*flag) {
        float4 f = *(const float4*)((const float*)src + i);
        u16 r[4] = {f2bf(f.x), f2bf(f.y), f2bf(f.z), f2bf(f.w)};
        *(uint2*)(d + i) = *(const uint2*)r;
    } else {
        *(uint2*)(d + i) = *(const uint2*)((const u16*)src + i);
    }
}

__global__ void kcvt(const void* __restrict__ src, u16* __restrict__ dst, int n,
                     const int* __restrict__ flag) {
    int i = (blockIdx.x * 256 + threadIdx.x) * 4;
    if (i >= n) return;
    if (*flag) {
        float4 f = *(const float4*)((const float*)src + i);
        u16 r[4] = {f2bf(f.x), f2bf(f.y), f2bf(f.z), f2bf(f.w)};
        *(uint2*)(dst + i) = *(const uint2*)r;
    } else {
        *(uint2*)(dst + i) = *(const uint2*)((const u16*)src + i);
    }
}

// biases: [bq 512][bk 512][bv 512][bo 512][bcoef 80] -> bf16 ws
__global__ void kbias(const void* __restrict__ bq, const void* __restrict__ bk,
                      const void* __restrict__ bv, const void* __restrict__ bo,
                      const void* __restrict__ bc, u16* __restrict__ dst,
                      const int* __restrict__ flag) {
    int t = threadIdx.x;  // 512
    bool f = *flag != 0;
    dst[t]        = f ? f2bf(((const float*)bq)[t]) : ((const u16*)bq)[t];
    dst[512 + t]  = f ? f2bf(((const float*)bk)[t]) : ((const u16*)bk)[t];
    dst[1024 + t] = f ? f2bf(((const float*)bv)[t]) : ((const u16*)bv)[t];
    dst[1536 + t] = f ? f2bf(((const float*)bo)[t]) : ((const u16*)bo)[t];
    if (t < 80)
        dst[2048 + t] = f ? f2bf(((const float*)bc)[t]) : ((const u16*)bc)[t];
}

// ---------------------------------------------------------------------------
// transpose the four 512x512 weight matrices (W[k][n] -> WT[n][k]), bf16 out
// ---------------------------------------------------------------------------
__global__ void ktrans512(const void* __restrict__ wq, const void* __restrict__ wk,
                          const void* __restrict__ wv, const void* __restrict__ wo,
                          u16* __restrict__ dst, const int* __restrict__ flag) {
    __shared__ u16 t[32][33];
    const void* srcs[4] = {wq, wk, wv, wo};
    const void* src = srcs[blockIdx.z];
    bool f = *flag != 0;
    u16* d = dst + (size_t)blockIdx.z * 512 * 512;
    int x0 = blockIdx.x * 32, y0 = blockIdx.y * 32;
    size_t si = (size_t)(y0 + threadIdx.y) * 512 + x0 + threadIdx.x;
    t[threadIdx.y][threadIdx.x] = f ? f2bf(((const float*)src)[si]) : ((const u16*)src)[si];
    __syncthreads();
    d[(size_t)(x0 + threadIdx.y) * 512 + y0 + threadIdx.x] = t[threadIdx.x][threadIdx.y];
}

// Wcoef (10,512,8) -> WcT[(n*8+h)][d], bf16
__global__ void kwct(const void* __restrict__ wc, u16* __restrict__ dst,
                     const int* __restrict__ flag) {
    int nh = blockIdx.x;  // 0..79
    int n = nh >> 3, h = nh & 7;
    bool f = *flag != 0;
    for (int d = threadIdx.x; d < 512; d += 64) {
        size_t si = ((size_t)n * 512 + d) * 8 + h;
        dst[nh * 512 + d] = f ? f2bf(((const float*)wc)[si]) : ((const u16*)wc)[si];
    }
}

// ---------------------------------------------------------------------------
// batched projection GEMM: z = 0,1,2 -> qp, kp, vT(transposed write).
// out[4096][512] = A[4096][512] @ BT^T + bias (all bf16, MFMA)
// ---------------------------------------------------------------------------
__global__ __launch_bounds__(256) void kgemm3(const u16* __restrict__ qkv, const u16* __restrict__ WT,
                                              const u16* __restrict__ bias, u16* __restrict__ qp,
                                              u16* __restrict__ kpj, u16* __restrict__ vT) {
    int z = blockIdx.z;
    const u16* A  = qkv + (size_t)z * 2097152;
    const u16* BT = WT + (size_t)z * 262144;
    const u16* bs = bias + z * 512;
    __shared__ u16 As[64][40];
    __shared__ u16 Bs[64][40];
    int tid = threadIdx.x;
    int w = tid >> 6, lane = tid & 63, quad = lane >> 4, col = lane & 15;
    int m0 = blockIdx.y * 64, n0 = blockIdx.x * 64;
    int wm = (w >> 1) * 32, wn = (w & 1) * 32;
    int sr = tid >> 2, sc = tid & 3;
    f32x4 acc[2][2] = {};
    for (int kt = 0; kt < 512; kt += 32) {
        __syncthreads();
        *(uint4*)&As[sr][sc * 8] = *(const uint4*)&A[(size_t)(m0 + sr) * 512 + kt + sc * 8];
        *(uint4*)&Bs[sr][sc * 8] = *(const uint4*)&BT[(size_t)(n0 + sr) * 512 + kt + sc * 8];
        __syncthreads();
        s16x8 a[2], b[2];
        a[0] = *(const s16x8*)&As[wm + col][quad * 8];
        a[1] = *(const s16x8*)&As[wm + 16 + col][quad * 8];
        b[0] = *(const s16x8*)&Bs[wn + col][quad * 8];
        b[1] = *(const s16x8*)&Bs[wn + 16 + col][quad * 8];
#pragma unroll
        for (int mi = 0; mi < 2; mi++)
#pragma unroll
            for (int ni = 0; ni < 2; ni++)
                acc[mi][ni] = __builtin_amdgcn_mfma_f32_16x16x32_bf16(a[mi], b[ni], acc[mi][ni], 0, 0, 0);
    }
    if (z < 2) {
        u16* out = z ? kpj : qp;
#pragma unroll
        for (int mi = 0; mi < 2; mi++)
#pragma unroll
            for (int ni = 0; ni < 2; ni++) {
                int n = n0 + wn + ni * 16 + col;
                float bv = bf2f(bs[n]);
#pragma unroll
                for (int r = 0; r < 4; r++) {
                    int m = m0 + wm + mi * 16 + quad * 4 + r;
                    out[(size_t)m * 512 + n] = f2bf(acc[mi][ni][r] + bv);
                }
            }
    } else {
        // transposed packed write: vT[b][d][s], 4 consecutive s per lane
#pragma unroll
        for (int mi = 0; mi < 2; mi++)
#pragma unroll
            for (int ni = 0; ni < 2; ni++) {
                int n = n0 + wn + ni * 16 + col;
                float bv = bf2f(bs[n]);
                int m = m0 + wm + mi * 16 + quad * 4;
                int bb = m >> 11, s = m & 2047;
                u16 pk4[4];
#pragma unroll
                for (int r = 0; r < 4; r++) pk4[r] = f2bf(acc[mi][ni][r] + bv);
                *(uint2*)&vT[((size_t)(bb * 512 + n)) * 2048 + s] = *(const uint2*)pk4;
            }
    }
}

// final GEMM: same compute, runtime dtype-selected store into d_out (1 launch)
__global__ __launch_bounds__(256) void kgemm_final(const u16* __restrict__ A, const u16* __restrict__ BT,
                                                   const u16* __restrict__ bias, u16* __restrict__ outH,
                                                   float* __restrict__ outF, const int* __restrict__ flag) {
    bool f32o = *flag != 0;
    __shared__ u16 As[64][40];
    __shared__ u16 Bs[64][40];
    int tid = threadIdx.x;
    int w = tid >> 6, lane = tid & 63, quad = lane >> 4, col = lane & 15;
    int m0 = blockIdx.y * 64, n0 = blockIdx.x * 64;
    int wm = (w >> 1) * 32, wn = (w & 1) * 32;
    int sr = tid >> 2, sc = tid & 3;
    f32x4 acc[2][2] = {};
    for (int kt = 0; kt < 512; kt += 32) {
        __syncthreads();
        *(uint4*)&As[sr][sc * 8] = *(const uint4*)&A[(size_t)(m0 + sr) * 512 + kt + sc * 8];
        *(uint4*)&Bs[sr][sc * 8] = *(const uint4*)&BT[(size_t)(n0 + sr) * 512 + kt + sc * 8];
        __syncthreads();
        s16x8 a[2], b[2];
        a[0] = *(const s16x8*)&As[wm + col][quad * 8];
        a[1] = *(const s16x8*)&As[wm + 16 + col][quad * 8];
        b[0] = *(const s16x8*)&Bs[wn + col][quad * 8];
        b[1] = *(const s16x8*)&Bs[wn + 16 + col][quad * 8];
#pragma unroll
        for (int mi = 0; mi < 2; mi++)
#pragma unroll
            for (int ni = 0; ni < 2; ni++)
                acc[mi][ni] = __builtin_amdgcn_mfma_f32_16x16x32_bf16(a[mi], b[ni], acc[mi][ni], 0, 0, 0);
    }
#pragma unroll
    for (int mi = 0; mi < 2; mi++)
#pragma unroll
        for (int ni = 0; ni < 2; ni++) {
            int n = n0 + wn + ni * 16 + col;
            float bv = bf2f(bias[n]);
#pragma unroll
            for (int r = 0; r < 4; r++) {
                int m = m0 + wm + mi * 16 + quad * 4 + r;
                float val = acc[mi][ni][r] + bv;
                if (f32o) outF[(size_t)m * 512 + n] = val;
                else      outH[(size_t)m * 512 + n] = f2bf(val);
            }
        }
}

// ---------------------------------------------------------------------------
// coefs[(b*8+h)*10+n][s] (fp32, pre-scaled by 0.0125, abs on n==1)
// MFMA version: out[4096][80] = qp @ WcT^T, one 64-row tile per block.
// ---------------------------------------------------------------------------
__global__ __launch_bounds__(256) void kcoef(const u16* __restrict__ qp, const u16* __restrict__ wct,
                                             const u16* __restrict__ bc, float* __restrict__ cout) {
    __shared__ u16 As[64][40];
    int tid = threadIdx.x;
    int w = tid >> 6, lane = tid & 63, quad = lane >> 4, col = lane & 15;
    int m0 = blockIdx.x * 64;
    int sr = tid >> 2, sc = tid & 3;
    f32x4 acc[5] = {};
    for (int kt = 0; kt < 512; kt += 32) {
        __syncthreads();
        *(uint4*)&As[sr][sc * 8] = *(const uint4*)&qp[(size_t)(m0 + sr) * 512 + kt + sc * 8];
        __syncthreads();
        s16x8 a = *(const s16x8*)&As[w * 16 + col][quad * 8];
#pragma unroll
        for (int nt = 0; nt < 5; nt++) {
            uint4 bv4 = *(const uint4*)&wct[(size_t)(nt * 16 + col) * 512 + kt + quad * 8];
            acc[nt] = __builtin_amdgcn_mfma_f32_16x16x32_bf16(a, __builtin_bit_cast(s16x8, bv4), acc[nt], 0, 0, 0);
        }
    }
    int m = m0 + w * 16 + quad * 4;
    int b = m >> 11, s = m & 2047;
#pragma unroll
    for (int nt = 0; nt < 5; nt++) {
        int nh = nt * 16 + col, n = nh >> 3, h = nh & 7;
        float bvv = bf2f(bc[nh]);
        float4 o;
        float tmp[4];
#pragma unroll
        for (int r = 0; r < 4; r++) {
            float c = acc[nt][r] + bvv;
            if (n == 1) c = fabsf(c);
            tmp[r] = c * 0.0125f;  // 0.1 * (1/sqrt(64))
        }
        o.x = tmp[0]; o.y = tmp[1]; o.z = tmp[2]; o.w = tmp[3];
        *(float4*)&cout[((size_t)((b * 8 + h) * 10 + n)) * 2048 + s] = o;
    }
}

// ---------------------------------------------------------------------------
// fused attention sweep, 8 waves (512 thr).
// Key structure changes vs prior rounds:
//  - xs is READ-ONLY in the k-loop; p~ goes to a separate ps buffer (no
//    LDS read/write aliasing -> x-reads hoist, no serialized lgkmcnt).
//  - all 16 x values are loaded into registers BEFORE the compute loop.
//  - sin/cos at {1,3,5,9}*pi*x computed DIRECTLY (8 independent HW trans
//    ops) instead of an 18-op serial multiple-angle chain.
// Per chunk: C prefetch (regs) | A QK+basis+exp->ps | B PV from ps |
// barrier | D vector p~ store from ps | E ds_write staged chunk | barrier.
// F32S=0: bf16 p~ -> attnH (flag 0) or pbuf (flag 1 & big ws).
// F32S=1: fp32 p~ -> attnF (flag 1, small-ws fallback; bf16-quantized).
// ---------------------------------------------------------------------------
template <int F32S>
__global__ __launch_bounds__(512) void kattn_t(const u16* __restrict__ qp, const u16* __restrict__ kp,
                                               const u16* __restrict__ vT, const u16* __restrict__ xd,
                                               const float* __restrict__ coef,
                                               u16* __restrict__ attnH, u16* __restrict__ pbuf,
                                               float* __restrict__ p32,
                                               u16* __restrict__ ctx, float* __restrict__ invb,
                                               const int* __restrict__ flag, int big) {
    int fl = *flag;
    if constexpr (F32S) { if (fl != 1) return; }        // only small-ws fp32 path
    else                { if (fl && !big) return; }      // fp32 handled by F32S=1
    u16* p16 = fl ? pbuf : attnH;

    __shared__ u16 qs[64][72];
    __shared__ u16 ks[128][72];
    __shared__ u16 xs[64][136];
    __shared__ u16 ps[64][136];
    __shared__ float cfl[10][64];

    int tid = threadIdx.x;
    int lane = tid & 63, quad = lane >> 4, col = lane & 15;
    int w = tid >> 6;
    int wr = w & 3, wc = w >> 2;
    int qt = blockIdx.x, bh = blockIdx.y;
    int b = bh >> 3, h = bh & 7;
    int q0 = qt * 64;

    // staging thread mappings (E and D use the SAME ps/xs byte-partition)
    int kr = tid >> 2, hf = tid & 3;   // ks: row kr, 16-col group hf
    int qr = tid >> 3, qu = tid & 7;   // xs/ps: row qr, 16-col group qu

    const u16* ksrc0 = kp + ((size_t)(b * 2048 + kr)) * 512 + h * 64 + hf * 16;
    const u16* xsrc0 = xd + ((size_t)(b * 2048 + q0 + qr)) * 2048 + qu * 16;

    // prefetch chunk 0 into regs
    uint4 kg0 = *(const uint4*)&ksrc0[0];
    uint4 kg1 = *(const uint4*)&ksrc0[8];
    uint4 xg0 = *(const uint4*)&xsrc0[0];
    uint4 xg1 = *(const uint4*)&xsrc0[8];

    // qs + cfl staging (overlaps the prefetch latency)
    {
        int r = tid >> 3, c8 = tid & 7;
        const u16* src = qp + ((size_t)(b * 2048 + q0 + r)) * 512 + h * 64 + c8 * 8;
        *(uint4*)&qs[r][c8 * 8] = *(const uint4*)src;
    }
    if (tid < 160) {
        int n = tid >> 4, i = tid & 15;
        *(float4*)&cfl[n][i * 4] = *(const float4*)&coef[((size_t)(bh * 10 + n)) * 2048 + q0 + i * 4];
    }
    // write staged chunk 0 (compiler waits vmcnt for kg/xg)
    *(uint4*)&ks[kr][hf * 16]     = kg0;
    *(uint4*)&ks[kr][hf * 16 + 8] = kg1;
    *(uint4*)&xs[qr][qu * 16]     = xg0;
    *(uint4*)&xs[qr][qu * 16 + 8] = xg1;
    __syncthreads();

    float cf[40];
#pragma unroll
    for (int n = 0; n < 10; n++)
#pragma unroll
        for (int r = 0; r < 4; r++) cf[n * 4 + r] = cfl[n][wr * 16 + quad * 4 + r];

    s16x8 a0 = *(const s16x8*)&qs[wr * 16 + col][quad * 8];
    s16x8 a1 = *(const s16x8*)&qs[wr * 16 + col][32 + quad * 8];

    float s_l[4] = {0.f, 0.f, 0.f, 0.f};
    f32x4 accv[4] = {};

    size_t abase = ((size_t)(bh * 2048 + q0)) * 2048;
    const u16* vb0 = vT + ((size_t)(b * 512 + h * 64 + col)) * 2048 + quad * 8;

    for (int c = 0; c < 16; c++) {
        int k0 = c * 128;
        // C: issue next-chunk prefetch (no wait; hides under A/B)
        if (c < 15) {
            const u16* ksrc = ksrc0 + (size_t)(k0 + 128) * 512;
            const u16* xsrc = xsrc0 + k0 + 128;
            kg0 = *(const uint4*)&ksrc[0];
            kg1 = *(const uint4*)&ksrc[8];
            xg0 = *(const uint4*)&xsrc[0];
            xg1 = *(const uint4*)&xsrc[8];
        }
        // hoisted x loads: xs is read-only in this loop -> all 16 ds_reads
        // issue back-to-back with no aliasing hazard
        float xv[16];
#pragma unroll
        for (int e = 0; e < 16; e++) {
            int nt = e >> 2, r = e & 3;
            xv[e] = bf2f(xs[wr * 16 + quad * 4 + r][(wc * 4 + nt) * 16 + col]);
        }
        // A: QK^T + basis + exp -> p~ into ps
#pragma unroll
        for (int nt = 0; nt < 4; nt++) {
            int ntg = wc * 4 + nt;
            s16x8 b0 = *(const s16x8*)&ks[ntg * 16 + col][quad * 8];
            s16x8 b1 = *(const s16x8*)&ks[ntg * 16 + col][32 + quad * 8];
            f32x4 acc = {0.f, 0.f, 0.f, 0.f};
            acc = __builtin_amdgcn_mfma_f32_16x16x32_bf16(a0, b0, acc, 0, 0, 0);
            acc = __builtin_amdgcn_mfma_f32_16x16x32_bf16(a1, b1, acc, 0, 0, 0);
#pragma unroll
            for (int r = 0; r < 4; r++) {
                int lq = wr * 16 + quad * 4 + r;
                int kk = ntg * 16 + col;
                float x = xv[nt * 4 + r];
                float a1g = PIf * x;
                // independent HW trans ops -- no serial chain
                float s1 = __sinf(a1g),        c1 = __cosf(a1g);
                float s3 = __sinf(3.f * a1g),  c3 = __cosf(3.f * a1g);
                float s5 = __sinf(5.f * a1g),  c5 = __cosf(5.f * a1g);
                float s9 = __sinf(9.f * a1g),  c9 = __cosf(9.f * a1g);
                float d0 = fmaf(cf[0 * 4 + r], x, cf[1 * 4 + r] * (-0.5f * x * x));
                float d1 = fmaf(cf[2 * 4 + r], s1, cf[3 * 4 + r] * c1);
                float d2 = fmaf(cf[4 * 4 + r], s3, cf[5 * 4 + r] * c3);
                float d3 = fmaf(cf[6 * 4 + r], s5, cf[7 * 4 + r] * c5);
                float d4 = fmaf(cf[8 * 4 + r], s9, cf[9 * 4 + r] * c9);
                float dot = (d0 + d1) + (d2 + d3) + d4;
                float logit = acc[r] * 0.125f + dot;
                float p = __expf(logit);
                s_l[r] += p;
                ps[lq][kk] = f2bf(p);  // separate buffer: no alias with xs reads
            }
        }
        // B: PV on this wave's k-half (wave-private ps sub-block)
#pragma unroll
        for (int kc2 = 0; kc2 < 2; kc2++) {
            int kc = wc * 2 + kc2;
            s16x8 af = *(const s16x8*)&ps[wr * 16 + col][kc * 32 + quad * 8];
#pragma unroll
            for (int nt = 0; nt < 4; nt++) {
                uint4 bv4 = *(const uint4*)&vb0[(size_t)nt * 16 * 2048 + k0 + kc * 32];
                accv[nt] = __builtin_amdgcn_mfma_f32_16x16x32_bf16(af, __builtin_bit_cast(s16x8, bv4), accv[nt], 0, 0, 0);
            }
        }
        __syncthreads();  // barrier1: all p~ of chunk c in ps
        // D: vectorized p~ store from ps
        {
            size_t gbase = abase + (size_t)qr * 2048 + k0 + qu * 16;
            uint4 v0 = *(const uint4*)&ps[qr][qu * 16];
            uint4 v1 = *(const uint4*)&ps[qr][qu * 16 + 8];
            if constexpr (F32S) {
                unsigned aa[8] = {v0.x, v0.y, v0.z, v0.w, v1.x, v1.y, v1.z, v1.w};
                float* dst = p32 + gbase;
#pragma unroll
                for (int j = 0; j < 4; j++) {
                    float4 o;
                    o.x = b2f_lo(aa[2 * j]);     o.y = b2f_hi(aa[2 * j]);
                    o.z = b2f_lo(aa[2 * j + 1]); o.w = b2f_hi(aa[2 * j + 1]);
                    *(float4*)&dst[j * 4] = o;
                }
            } else {
                u16* dst = p16 + gbase;
                *(uint4*)&dst[0] = v0;
                *(uint4*)&dst[8] = v1;
            }
        }
        // E: write staged next chunk (xs/ks only; ps untouched)
        if (c < 15) {
            *(uint4*)&ks[kr][hf * 16]     = kg0;
            *(uint4*)&ks[kr][hf * 16 + 8] = kg1;
            *(uint4*)&xs[qr][qu * 16]     = xg0;
            *(uint4*)&xs[qr][qu * 16 + 8] = xg1;
        }
        __syncthreads();  // barrier2
    }

    // partial row sums across the 16 lanes of each quad
    float sred[4];
#pragma unroll
    for (int r = 0; r < 4; r++) {
        float s = s_l[r];
#pragma unroll
        for (int off = 1; off < 16; off <<= 1) s += __shfl_xor(s, off);
        sred[r] = s;
    }

    // cross-wave (wc) combine through reclaimed LDS (loop exits after barrier2)
    float* red  = (float*)&ks[0][0];  // [4][64][16] = 16 KB (ks is 18 KB)
    float* psum = (float*)&xs[0][0];  // [64] partial sums from wc==1
    if (wc == 1) {
#pragma unroll
        for (int nt = 0; nt < 4; nt++)
#pragma unroll
            for (int r = 0; r < 4; r++)
                red[(wr * 64 + lane) * 16 + nt * 4 + r] = accv[nt][r];
        if (col == 0) {
#pragma unroll
            for (int r = 0; r < 4; r++) psum[wr * 16 + quad * 4 + r] = sred[r];
        }
    }
    __syncthreads();
    if (wc == 0) {
        float inv_r[4];
#pragma unroll
        for (int r = 0; r < 4; r++)
            inv_r[r] = 1.f / (sred[r] + psum[wr * 16 + quad * 4 + r]);
        if (col == 0) {
#pragma unroll
            for (int r = 0; r < 4; r++)
                invb[bh * 2048 + q0 + wr * 16 + quad * 4 + r] = inv_r[r];
        }
#pragma unroll
        for (int nt = 0; nt < 4; nt++)
#pragma unroll
            for (int r = 0; r < 4; r++) {
                float vsum = accv[nt][r] + red[(wr * 64 + lane) * 16 + nt * 4 + r];
                int q = q0 + wr * 16 + quad * 4 + r;
                int d = h * 64 + nt * 16 + col;
                ctx[((size_t)(b * 2048 + q)) * 512 + d] = f2bf(vsum * inv_r[r]);
            }
    }
}

// ---------------------------------------------------------------------------
// normalize p~ -> attn output, one launch. One block per attention row.
// flag==0: bf16 in-place on attnH. flag==1 & BIG: pbuf -> fp32 attnF.
// flag==1 & !BIG: fp32 in-place on attnF.
// ---------------------------------------------------------------------------
template <int BIG>
__global__ __launch_bounds__(256) void knorm(u16* __restrict__ attnH, const u16* __restrict__ pbuf,
                                             float* __restrict__ attnF,
                                             const float* __restrict__ invb, const int* __restrict__ flag) {
    int fl = *flag;
    int row = blockIdx.x;  // 0..32767 = bh*2048 + q
    float inv = invb[row];
    size_t base = (size_t)row * 2048 + threadIdx.x * 8;
    if (fl == 0) {
        uint4 vv = *(const uint4*)&attnH[base];
        unsigned a[4] = {vv.x, vv.y, vv.z, vv.w};
#pragma unroll
        for (int i = 0; i < 4; i++) {
            float lo = b2f_lo(a[i]) * inv;
            float hi = b2f_hi(a[i]) * inv;
            a[i] = ((unsigned)f2bf(hi) << 16) | (unsigned)f2bf(lo);
        }
        uint4 o; o.x = a[0]; o.y = a[1]; o.z = a[2]; o.w = a[3];
        *(uint4*)&attnH[base] = o;
    } else if constexpr (BIG) {
        uint4 vv = *(const uint4*)&pbuf[base];
        unsigned a[4] = {vv.x, vv.y, vv.z, vv.w};
        float4 o0, o1;
        o0.x = b2f_lo(a[0]) * inv; o0.y = b2f_hi(a[0]) * inv;
        o0.z = b2f_lo(a[1]) * inv; o0.w = b2f_hi(a[1]) * inv;
        o1.x = b2f_lo(a[2]) * inv; o1.y = b2f_hi(a[2]) * inv;
        o1.z = b2f_lo(a[3]) * inv; o1.w = b2f_hi(a[3]) * inv;
        *(float4*)&attnF[base] = o0;
        *(float4*)&attnF[base + 4] = o1;
    } else {
        float4 v0 = *(const float4*)&attnF[base];
        float4 v1 = *(const float4*)&attnF[base + 4];
        v0.x *= inv; v0.y *= inv; v0.z *= inv; v0.w *= inv;
        v1.x *= inv; v1.y *= inv; v1.z *= inv; v1.w *= inv;
        *(float4*)&attnF[base] = v0;
        *(float4*)&attnF[base + 4] = v1;
    }
}

// ---------------------------------------------------------------------------
// launch
// ---------------------------------------------------------------------------
extern "C" void kernel_launch(void* const* d_in, const int* in_sizes, int n_in,
                              void* d_out, int out_size, void* d_ws, size_t ws_size,
                              hipStream_t stream) {
    const void* q  = d_in[0];
    const void* k  = d_in[1];
    const void* v  = d_in[2];
    const void* xd = d_in[3];
    const void* Wq = d_in[4];
    const void* bq = d_in[5];
    const void* Wk = d_in[6];
    const void* bk = d_in[7];
    const void* Wv = d_in[8];
    const void* bv = d_in[9];
    const void* Wc = d_in[10];
    const void* bc = d_in[11];
    const void* Wo = d_in[12];
    const void* bo = d_in[13];

    char* ws = (char*)d_ws;
    int*   flag = (int*)(ws + OFF_FLAG);
    u16*   WT   = (u16*)(ws + OFF_WT);
    u16*   WcT  = (u16*)(ws + OFF_WCT);
    u16*   qb   = (u16*)(ws + OFF_QB);
    u16*   xb   = (u16*)(ws + OFF_XB);
    u16*   qp   = (u16*)(ws + OFF_QP);
    u16*   kp   = (u16*)(ws + OFF_KP);
    u16*   vT   = (u16*)(ws + OFF_VT);
    float* coef = (float*)(ws + OFF_COEF);
    u16*   ctx  = (u16*)(ws + OFF_CTX);
    u16*   bB   = (u16*)(ws + OFF_BIAS);
    float* invb = (float*)(ws + OFF_INV);
    u16*   pbuf = (u16*)(ws + OFF_PBUF);

    u16*   outH  = (u16*)d_out;
    u16*   attnH = outH + 2097152;
    float* outF  = (float*)d_out;
    float* attnF = outF + 2097152;

    // bf16 p~ staging buffer needs 134 MB of ws; fall back to fp32-in-place if absent
    bool big = ws_size >= (size_t)OFF_PBUF + 134217728ull;

    kdetect<<<1, 64, 0, stream>>>((const u32*)Wq, flag);
    kcvt3<<<dim3(2048, 3), 256, 0, stream>>>(q, k, v, qb, flag);
    kcvt<<<8192, 256, 0, stream>>>(xd, xb, 8388608, flag);
    kbias<<<1, 512, 0, stream>>>(bq, bk, bv, bo, bc, bB, flag);
    ktrans512<<<dim3(16, 16, 4), dim3(32, 32), 0, stream>>>(Wq, Wk, Wv, Wo, WT, flag);
    kwct<<<80, 64, 0, stream>>>(Wc, WcT, flag);
    kgemm3<<<dim3(8, 64, 3), 256, 0, stream>>>(qb, WT, bB, qp, kp, vT);
    kcoef<<<64, 256, 0, stream>>>(qp, WcT, bB + 2048, coef);

    kattn_t<0><<<dim3(32, 16), 512, 0, stream>>>(qp, kp, vT, xb, coef, attnH, pbuf, attnF,
                                                 ctx, invb, flag, (int)big);
    if (!big)
        kattn_t<1><<<dim3(32, 16), 512, 0, stream>>>(qp, kp, vT, xb, coef, attnH, pbuf, attnF,
                                                     ctx, invb, flag, 0);

    if (big) knorm<1><<<32768, 256, 0, stream>>>(attnH, pbuf, attnF, invb, flag);
    else     knorm<0><<<32768, 256, 0, stream>>>(attnH, pbuf, attnF, invb, flag);

    kgemm_final<<<dim3(8, 64), 256, 0, stream>>>(ctx, WT + 786432, bB + 1536, outH, outF, flag);
}